// Round 6
// baseline (152.668 us; speedup 1.0000x reference)
//
#include <hip/hip_runtime.h>
#include <hip/hip_bf16.h>
#include <hip/hip_fp16.h>
#include <stdint.h>

#define NB 2048
#define NU 512
#define NL 32
#define NH 64

typedef float    f4    __attribute__((ext_vector_type(4)));
typedef uint32_t u32x4 __attribute__((ext_vector_type(4)));
typedef _Float16 h8    __attribute__((ext_vector_type(8)));

__device__ __forceinline__ f4 mfma16h(u32x4 a, u32x4 b, f4 c) {
    return __builtin_amdgcn_mfma_f32_16x16x32_f16(
        __builtin_bit_cast(h8, a), __builtin_bit_cast(h8, b), c, 0, 0, 0);
}

// RNE fp16 pair pack: low = h(a), high = h(b). (staging, one-time)
__device__ __forceinline__ uint32_t pk2h(float a, float b) {
    uint32_t la = (uint32_t)__half_as_ushort(__float2half_rn(a));
    uint32_t hb = (uint32_t)__half_as_ushort(__float2half_rn(b));
    return la | (hb << 16);
}

// RTZ fp16 pack (activations, 1 VALU op)
__device__ __forceinline__ uint32_t pk_rtz(float e, float o) {
    return __builtin_bit_cast(uint32_t, __builtin_amdgcn_cvt_pkrtz(e, o));
}

// bf16 pack of a pair (bias storage; 1-op unpack via shift/and)
__device__ __forceinline__ uint32_t rpk(float e, float o) {
    return __builtin_amdgcn_perm(__float_as_uint(o) + 0x8000u,
                                 __float_as_uint(e) + 0x8000u, 0x07060302u);
}

// act exchange: 4x16-lane-group block transpose via permlane swaps (pure, non-volatile)
__device__ __forceinline__ void xch(uint32_t A, uint32_t B,
                                    uint32_t& o0, uint32_t& o1) {
    asm("v_permlane32_swap_b32 %0, %1" : "+v"(A), "+v"(B));
    asm("v_permlane16_swap_b32 %0, %1" : "+v"(A), "+v"(B));
    o0 = A; o1 = B;
}

// ---------------------------------------------------------------- encoder ---
__global__ __launch_bounds__(256)
void enc_kernel(const float* __restrict__ x,
                const float* __restrict__ We1, const float* __restrict__ be1,
                const float* __restrict__ We2, const float* __restrict__ be2,
                const float* __restrict__ We3, const float* __restrict__ be3,
                const float* __restrict__ We4, const float* __restrict__ be4,
                float* __restrict__ z)
{
    const int RE = 8;
    __shared__ float xs[RE][512];
    __shared__ float ws[128 * 64];
    __shared__ float h[RE][NH];
    __shared__ float h2s[RE][NH];

    const int t  = threadIdx.x;
    const int r0 = blockIdx.x * RE;

    {
        const f4* xv  = (const f4*)(x + (size_t)r0 * 512);
        f4*       xsv = (f4*)&xs[0][0];
        for (int i = t; i < RE * 512 / 4; i += 256) xsv[i] = xv[i];
    }

    const int j = t & 63;
    const int w = t >> 6;

    float acc0 = be1[j], acc1 = be1[j];
    for (int kc = 0; kc < 512; kc += 128) {
        __syncthreads();
        const f4* wv  = (const f4*)(We1 + (size_t)kc * 64);
        f4*       wsv = (f4*)ws;
        for (int i = t; i < 128 * 64 / 4; i += 256) wsv[i] = wv[i];
        __syncthreads();
        #pragma unroll 8
        for (int k = 0; k < 128; ++k) {
            float wval = ws[k * 64 + j];
            acc0 = fmaf(xs[w][kc + k],     wval, acc0);
            acc1 = fmaf(xs[w + 4][kc + k], wval, acc1);
        }
    }
    acc0 = fmaxf(acc0, 0.f); acc1 = fmaxf(acc1, 0.f);
    __syncthreads();
    h[w][j] = acc0; h[w + 4][j] = acc1;
    __syncthreads();

    acc0 = be2[j]; acc1 = be2[j];
    #pragma unroll
    for (int k = 0; k < 64; ++k) {
        float wval = We2[k * 64 + j];
        acc0 = fmaf(h[w][k],     wval, acc0);
        acc1 = fmaf(h[w + 4][k], wval, acc1);
    }
    acc0 = fmaxf(acc0, 0.f); acc1 = fmaxf(acc1, 0.f);
    h2s[w][j] = acc0; h2s[w + 4][j] = acc1;
    __syncthreads();

    acc0 = be3[j]; acc1 = be3[j];
    #pragma unroll
    for (int k = 0; k < 64; ++k) {
        float wval = We3[k * 64 + j];
        acc0 = fmaf(h2s[w][k],     wval, acc0);
        acc1 = fmaf(h2s[w + 4][k], wval, acc1);
    }
    acc0 = fmaxf(acc0, 0.f); acc1 = fmaxf(acc1, 0.f);
    h[w][j] = acc0; h[w + 4][j] = acc1;
    __syncthreads();

    const int j4  = t & 31;
    const int row = t >> 5;
    float acc = be4[j4];
    #pragma unroll
    for (int k = 0; k < 64; ++k)
        acc = fmaf(h[row][k], We4[k * 32 + j4], acc);
    z[(size_t)r0 * 32 + t] = acc;
}

// ---------------------------------------------------------------- decoder ---
// 1024 blocks = 2 per unit (batch halves), 4 waves x 16 rows, 16 iters each.
// fp16-packed weights in LDS (23 KB) -> 4 blocks/CU, 16 waves/CU (50% occ).
// fp16 single-term MFMA, permlane exchange, unit swizzle vs out false-sharing.
template <int K2>
__device__ __forceinline__ void stageW(const float* __restrict__ g,
                                       uint32_t (*dst)[68], int t)
{
    for (int g4 = t; g4 < K2 * 16; g4 += 256) {
        const int k2 = g4 >> 4, c4 = (g4 & 15) << 2;
        f4 a = *(const f4*)(g + (size_t)(2 * k2) * NH + c4);
        f4 b = *(const f4*)(g + (size_t)(2 * k2 + 1) * NH + c4);
        u32x4 p;
        p[0] = pk2h(a[0], b[0]);
        p[1] = pk2h(a[1], b[1]);
        p[2] = pk2h(a[2], b[2]);
        p[3] = pk2h(a[3], b[3]);
        *(u32x4*)&dst[k2][c4] = p;
    }
}

__global__ __launch_bounds__(256, 4)
void dec_kernel(const float* __restrict__ z,
                const float* __restrict__ Wd1, const float* __restrict__ bd1,
                const float* __restrict__ Wd2, const float* __restrict__ bd2,
                const float* __restrict__ Wd3, const float* __restrict__ bd3,
                const float* __restrict__ Wd4, const float* __restrict__ bd4,
                float* __restrict__ out)
{
    __shared__ uint32_t wpk1[16][68];   // fp16-pair packed W1^ (pad 68: 2-way free)
    __shared__ uint32_t wpk2[32][68];
    __shared__ uint32_t wpk3[32][68];
    __shared__ float bsh[3][NH];
    __shared__ float w4s[NH];

    const int bid  = blockIdx.x;
    const int half = bid >> 9;          // batch half: iters [half*16, half*16+16)
    const int ub   = bid & 511;
    // bijective unit swizzle: 16 consecutive u (one 64B out-line) share bid%8 -> one XCD
    const int u = ((ub & 7) << 4) | (((ub >> 3) & 3) << 7) | (ub >> 5);
    const int t = threadIdx.x;

    stageW<16>(Wd1 + (size_t)u * NL * NH, wpk1, t);
    stageW<32>(Wd2 + (size_t)u * NH * NH, wpk2, t);
    stageW<32>(Wd3 + (size_t)u * NH * NH, wpk3, t);
    if (t < NH) {
        bsh[0][t] = bd1[(size_t)u * NH + t];
        bsh[1][t] = bd2[(size_t)u * NH + t];
        bsh[2][t] = bd3[(size_t)u * NH + t];
        w4s[t]    = Wd4[(size_t)u * NH + t];
    }
    __syncthreads();

    const int w  = t >> 6;          // wave 0..3
    const int lr = t & 15;          // batch-row lane
    const int lg = (t & 63) >> 4;   // lane group 0..3
    const float b4 = bd4[u];

    // ---- register A-fragments (W^T), packed fp16 pairs from LDS ----
    u32x4 a1[4], a2[4][2], a3[4][2];
    #pragma unroll
    for (int mt = 0; mt < 4; ++mt) {
        const int c = lr + 16 * mt;
        #pragma unroll
        for (int i = 0; i < 4; ++i)
            a1[mt][i] = wpk1[lg * 4 + i][c];
        #pragma unroll
        for (int ks = 0; ks < 2; ++ks) {
            #pragma unroll
            for (int i = 0; i < 4; ++i) {
                a2[mt][ks][i] = wpk2[ks * 16 + lg * 4 + i][c];
                a3[mt][ks][i] = wpk3[ks * 16 + lg * 4 + i][c];
            }
        }
    }

    // biases as packed bf16 pairs (1-op unpack per word)
    uint32_t bpk1[4][2], bpk2[4][2], bpk3[4][2];
    #pragma unroll
    for (int mt = 0; mt < 4; ++mt) {
        const int c = 16 * mt + lg * 4;
        bpk1[mt][0] = rpk(bsh[0][c], bsh[0][c + 1]);
        bpk1[mt][1] = rpk(bsh[0][c + 2], bsh[0][c + 3]);
        bpk2[mt][0] = rpk(bsh[1][c], bsh[1][c + 1]);
        bpk2[mt][1] = rpk(bsh[1][c + 2], bsh[1][c + 3]);
        bpk3[mt][0] = rpk(bsh[2][c], bsh[2][c + 1]);
        bpk3[mt][1] = rpk(bsh[2][c + 2], bsh[2][c + 3]);
    }

    // per-lane Wd4 values: cols 16*mt + lg*4 + r
    f4 wd4v[4];
    #pragma unroll
    for (int mt = 0; mt < 4; ++mt)
        wd4v[mt] = *(const f4*)&w4s[16 * mt + lg * 4];

    const int rl  = w * 16 + lr;        // block-local row of this lane
    const int it0 = half * 16;

    f4 zc0 = *(const f4*)(z + (size_t)(it0 * 64 + rl) * NL + lg * 8);
    f4 zc1 = *(const f4*)(z + (size_t)(it0 * 64 + rl) * NL + lg * 8 + 4);

    for (int it = it0; it < it0 + 16; ++it) {
        const int row = it * 64 + rl;
        const int rnext = (it0 + ((it - it0 + 1) & 15)) * 64 + rl;
        f4 zn0 = *(const f4*)(z + (size_t)rnext * NL + lg * 8);
        f4 zn1 = *(const f4*)(z + (size_t)rnext * NL + lg * 8 + 4);

        // ---- L1: B-frag from z ----
        u32x4 bh;
        bh[0] = pk_rtz(zc0[0], zc0[1]);
        bh[1] = pk_rtz(zc0[2], zc0[3]);
        bh[2] = pk_rtz(zc1[0], zc1[1]);
        bh[3] = pk_rtz(zc1[2], zc1[3]);

        f4 acc[4];
        #pragma unroll
        for (int mt = 0; mt < 4; ++mt) {
            acc[mt][0] = __uint_as_float(bpk1[mt][0] << 16);
            acc[mt][1] = __uint_as_float(bpk1[mt][0] & 0xFFFF0000u);
            acc[mt][2] = __uint_as_float(bpk1[mt][1] << 16);
            acc[mt][3] = __uint_as_float(bpk1[mt][1] & 0xFFFF0000u);
            acc[mt] = mfma16h(a1[mt], bh, acc[mt]);
        }

        // relu + pack h1
        uint32_t pk[4][2];
        #pragma unroll
        for (int mt = 0; mt < 4; ++mt) {
            pk[mt][0] = pk_rtz(fmaxf(acc[mt][0], 0.f), fmaxf(acc[mt][1], 0.f));
            pk[mt][1] = pk_rtz(fmaxf(acc[mt][2], 0.f), fmaxf(acc[mt][3], 0.f));
        }

        // ---- L2 ----
        #pragma unroll
        for (int mt = 0; mt < 4; ++mt) {
            acc[mt][0] = __uint_as_float(bpk2[mt][0] << 16);
            acc[mt][1] = __uint_as_float(bpk2[mt][0] & 0xFFFF0000u);
            acc[mt][2] = __uint_as_float(bpk2[mt][1] << 16);
            acc[mt][3] = __uint_as_float(bpk2[mt][1] & 0xFFFF0000u);
        }
        #pragma unroll
        for (int ks = 0; ks < 2; ++ks) {
            u32x4 bf;
            {
                uint32_t b0, b2, b1, b3;
                xch(pk[2 * ks][0], pk[2 * ks + 1][0], b0, b2);
                xch(pk[2 * ks][1], pk[2 * ks + 1][1], b1, b3);
                bf[0] = b0; bf[1] = b1; bf[2] = b2; bf[3] = b3;
            }
            #pragma unroll
            for (int mt = 0; mt < 4; ++mt)
                acc[mt] = mfma16h(a2[mt][ks], bf, acc[mt]);
        }

        // relu + pack h2
        uint32_t pk2_[4][2];
        #pragma unroll
        for (int mt = 0; mt < 4; ++mt) {
            pk2_[mt][0] = pk_rtz(fmaxf(acc[mt][0], 0.f), fmaxf(acc[mt][1], 0.f));
            pk2_[mt][1] = pk_rtz(fmaxf(acc[mt][2], 0.f), fmaxf(acc[mt][3], 0.f));
        }

        // ---- L3 ----
        #pragma unroll
        for (int mt = 0; mt < 4; ++mt) {
            acc[mt][0] = __uint_as_float(bpk3[mt][0] << 16);
            acc[mt][1] = __uint_as_float(bpk3[mt][0] & 0xFFFF0000u);
            acc[mt][2] = __uint_as_float(bpk3[mt][1] << 16);
            acc[mt][3] = __uint_as_float(bpk3[mt][1] & 0xFFFF0000u);
        }
        #pragma unroll
        for (int ks = 0; ks < 2; ++ks) {
            u32x4 bf;
            {
                uint32_t b0, b2, b1, b3;
                xch(pk2_[2 * ks][0], pk2_[2 * ks + 1][0], b0, b2);
                xch(pk2_[2 * ks][1], pk2_[2 * ks + 1][1], b1, b3);
                bf[0] = b0; bf[1] = b1; bf[2] = b2; bf[3] = b3;
            }
            #pragma unroll
            for (int mt = 0; mt < 4; ++mt)
                acc[mt] = mfma16h(a3[mt][ks], bf, acc[mt]);
        }

        // ---- L4: fp32 dot with wd4 ----
        float part = 0.f;
        #pragma unroll
        for (int mt = 0; mt < 4; ++mt) {
            part = fmaf(fmaxf(acc[mt][0], 0.f), wd4v[mt][0], part);
            part = fmaf(fmaxf(acc[mt][1], 0.f), wd4v[mt][1], part);
            part = fmaf(fmaxf(acc[mt][2], 0.f), wd4v[mt][2], part);
            part = fmaf(fmaxf(acc[mt][3], 0.f), wd4v[mt][3], part);
        }
        part += __shfl_xor(part, 16);
        part += __shfl_xor(part, 32);
        if ((t & 48) == 0)
            out[(size_t)row * NU + u] = part + b4;

        zc0 = zn0; zc1 = zn1;
    }
}

// ----------------------------------------------------------------- launch ---
extern "C" void kernel_launch(void* const* d_in, const int* in_sizes, int n_in,
                              void* d_out, int out_size, void* d_ws, size_t ws_size,
                              hipStream_t stream)
{
    const float* x   = (const float*)d_in[0];
    const float* We1 = (const float*)d_in[1];
    const float* be1 = (const float*)d_in[2];
    const float* We2 = (const float*)d_in[3];
    const float* be2 = (const float*)d_in[4];
    const float* We3 = (const float*)d_in[5];
    const float* be3 = (const float*)d_in[6];
    const float* We4 = (const float*)d_in[7];
    const float* be4 = (const float*)d_in[8];
    const float* Wd1 = (const float*)d_in[9];
    const float* bd1 = (const float*)d_in[10];
    const float* Wd2 = (const float*)d_in[11];
    const float* bd2 = (const float*)d_in[12];
    const float* Wd3 = (const float*)d_in[13];
    const float* bd3 = (const float*)d_in[14];
    const float* Wd4 = (const float*)d_in[15];
    const float* bd4 = (const float*)d_in[16];
    float* out = (float*)d_out;

    float* zbuf = (float*)d_ws;   // 256 KB scratch

    enc_kernel<<<NB / 8, 256, 0, stream>>>(x, We1, be1, We2, be2, We3, be3,
                                           We4, be4, zbuf);
    dec_kernel<<<NU * 2, 256, 0, stream>>>(zbuf, Wd1, bd1, Wd2, bd2,
                                           Wd3, bd3, Wd4, bd4, out);
}

// Round 7
// 143.128 us; speedup vs baseline: 1.0667x; 1.0667x over previous
//
#include <hip/hip_runtime.h>
#include <hip/hip_bf16.h>
#include <hip/hip_fp16.h>
#include <stdint.h>

#define NB 2048
#define NU 512
#define NL 32
#define NH 64

typedef float    f4    __attribute__((ext_vector_type(4)));
typedef uint32_t u32x4 __attribute__((ext_vector_type(4)));
typedef _Float16 h8    __attribute__((ext_vector_type(8)));

__device__ __forceinline__ f4 mfma16h(u32x4 a, u32x4 b, f4 c) {
    return __builtin_amdgcn_mfma_f32_16x16x32_f16(
        __builtin_bit_cast(h8, a), __builtin_bit_cast(h8, b), c, 0, 0, 0);
}

// RNE fp16 pair pack: low = h(a), high = h(b). (staging, one-time)
__device__ __forceinline__ uint32_t pk2h(float a, float b) {
    uint32_t la = (uint32_t)__half_as_ushort(__float2half_rn(a));
    uint32_t hb = (uint32_t)__half_as_ushort(__float2half_rn(b));
    return la | (hb << 16);
}

// RTZ fp16 pack (activations, 1 VALU op)
__device__ __forceinline__ uint32_t pk_rtz(float e, float o) {
    return __builtin_bit_cast(uint32_t, __builtin_amdgcn_cvt_pkrtz(e, o));
}

// bf16 pack of a pair (bias storage; 1-op unpack via shift/and)
__device__ __forceinline__ uint32_t rpk(float e, float o) {
    return __builtin_amdgcn_perm(__float_as_uint(o) + 0x8000u,
                                 __float_as_uint(e) + 0x8000u, 0x07060302u);
}

// act exchange: 4x16-lane-group block transpose via permlane swaps
__device__ __forceinline__ void xch(uint32_t A, uint32_t B,
                                    uint32_t& o0, uint32_t& o1) {
    asm("v_permlane32_swap_b32 %0, %1" : "+v"(A), "+v"(B));
    asm("v_permlane16_swap_b32 %0, %1" : "+v"(A), "+v"(B));
    o0 = A; o1 = B;
}

// ---------------------------------------------------------------- encoder ---
__global__ __launch_bounds__(256)
void enc_kernel(const float* __restrict__ x,
                const float* __restrict__ We1, const float* __restrict__ be1,
                const float* __restrict__ We2, const float* __restrict__ be2,
                const float* __restrict__ We3, const float* __restrict__ be3,
                const float* __restrict__ We4, const float* __restrict__ be4,
                float* __restrict__ z)
{
    const int RE = 8;
    __shared__ float xs[RE][512];
    __shared__ float ws[128 * 64];
    __shared__ float h[RE][NH];
    __shared__ float h2s[RE][NH];

    const int t  = threadIdx.x;
    const int r0 = blockIdx.x * RE;

    {
        const f4* xv  = (const f4*)(x + (size_t)r0 * 512);
        f4*       xsv = (f4*)&xs[0][0];
        for (int i = t; i < RE * 512 / 4; i += 256) xsv[i] = xv[i];
    }

    const int j = t & 63;
    const int w = t >> 6;

    float acc0 = be1[j], acc1 = be1[j];
    for (int kc = 0; kc < 512; kc += 128) {
        __syncthreads();
        const f4* wv  = (const f4*)(We1 + (size_t)kc * 64);
        f4*       wsv = (f4*)ws;
        for (int i = t; i < 128 * 64 / 4; i += 256) wsv[i] = wv[i];
        __syncthreads();
        #pragma unroll 8
        for (int k = 0; k < 128; ++k) {
            float wval = ws[k * 64 + j];
            acc0 = fmaf(xs[w][kc + k],     wval, acc0);
            acc1 = fmaf(xs[w + 4][kc + k], wval, acc1);
        }
    }
    acc0 = fmaxf(acc0, 0.f); acc1 = fmaxf(acc1, 0.f);
    __syncthreads();
    h[w][j] = acc0; h[w + 4][j] = acc1;
    __syncthreads();

    acc0 = be2[j]; acc1 = be2[j];
    #pragma unroll
    for (int k = 0; k < 64; ++k) {
        float wval = We2[k * 64 + j];
        acc0 = fmaf(h[w][k],     wval, acc0);
        acc1 = fmaf(h[w + 4][k], wval, acc1);
    }
    acc0 = fmaxf(acc0, 0.f); acc1 = fmaxf(acc1, 0.f);
    h2s[w][j] = acc0; h2s[w + 4][j] = acc1;
    __syncthreads();

    acc0 = be3[j]; acc1 = be3[j];
    #pragma unroll
    for (int k = 0; k < 64; ++k) {
        float wval = We3[k * 64 + j];
        acc0 = fmaf(h2s[w][k],     wval, acc0);
        acc1 = fmaf(h2s[w + 4][k], wval, acc1);
    }
    acc0 = fmaxf(acc0, 0.f); acc1 = fmaxf(acc1, 0.f);
    h[w][j] = acc0; h[w + 4][j] = acc1;
    __syncthreads();

    const int j4  = t & 31;
    const int row = t >> 5;
    float acc = be4[j4];
    #pragma unroll
    for (int k = 0; k < 64; ++k)
        acc = fmaf(h[row][k], We4[k * 32 + j4], acc);
    z[(size_t)r0 * 32 + t] = acc;
}

// ---------------------------------------------------------------- decoder ---
// 1024 blocks = 2 per unit (batch halves), 4 waves x 16 rows, 16 iters each.
// waves_per_eu(4,4): pin exactly 4 waves/EU -> VGPR budget 128, no
// occupancy-chasing spill (round 6: launch_bounds(256,4) made the allocator
// target 8 waves/EU at 64 VGPRs and spill the frags to scratch = 436 MB HBM).
template <int K2>
__device__ __forceinline__ void stageW(const float* __restrict__ g,
                                       uint32_t (*dst)[68], int t)
{
    for (int g4 = t; g4 < K2 * 16; g4 += 256) {
        const int k2 = g4 >> 4, c4 = (g4 & 15) << 2;
        f4 a = *(const f4*)(g + (size_t)(2 * k2) * NH + c4);
        f4 b = *(const f4*)(g + (size_t)(2 * k2 + 1) * NH + c4);
        u32x4 p;
        p[0] = pk2h(a[0], b[0]);
        p[1] = pk2h(a[1], b[1]);
        p[2] = pk2h(a[2], b[2]);
        p[3] = pk2h(a[3], b[3]);
        *(u32x4*)&dst[k2][c4] = p;
    }
}

__global__ __launch_bounds__(256) __attribute__((amdgpu_waves_per_eu(4, 4)))
void dec_kernel(const float* __restrict__ z,
                const float* __restrict__ Wd1, const float* __restrict__ bd1,
                const float* __restrict__ Wd2, const float* __restrict__ bd2,
                const float* __restrict__ Wd3, const float* __restrict__ bd3,
                const float* __restrict__ Wd4, const float* __restrict__ bd4,
                float* __restrict__ out)
{
    __shared__ uint32_t wpk1[16][68];   // fp16-pair packed W^T (pad 68: 2-way free)
    __shared__ uint32_t wpk2[32][68];
    __shared__ uint32_t wpk3[32][68];
    __shared__ float bsh[3][NH];
    __shared__ float w4s[NH];

    const int bid  = blockIdx.x;
    const int half = bid >> 9;          // batch half: iters [half*16, half*16+16)
    const int ub   = bid & 511;
    // bijective unit swizzle: 16 consecutive u (one 64B out-line) share bid%8 -> one XCD
    const int u = ((ub & 7) << 4) | (((ub >> 3) & 3) << 7) | (ub >> 5);
    const int t = threadIdx.x;

    stageW<16>(Wd1 + (size_t)u * NL * NH, wpk1, t);
    stageW<32>(Wd2 + (size_t)u * NH * NH, wpk2, t);
    stageW<32>(Wd3 + (size_t)u * NH * NH, wpk3, t);
    if (t < NH) {
        bsh[0][t] = bd1[(size_t)u * NH + t];
        bsh[1][t] = bd2[(size_t)u * NH + t];
        bsh[2][t] = bd3[(size_t)u * NH + t];
        w4s[t]    = Wd4[(size_t)u * NH + t];
    }
    __syncthreads();

    const int w  = t >> 6;          // wave 0..3
    const int lr = t & 15;          // batch-row lane
    const int lg = (t & 63) >> 4;   // lane group 0..3
    const float b4 = bd4[u];

    // ---- register A-fragments (W^T), packed fp16 pairs from LDS ----
    u32x4 a1[4], a2[4][2], a3[4][2];
    #pragma unroll
    for (int mt = 0; mt < 4; ++mt) {
        const int c = lr + 16 * mt;
        #pragma unroll
        for (int i = 0; i < 4; ++i)
            a1[mt][i] = wpk1[lg * 4 + i][c];
        #pragma unroll
        for (int ks = 0; ks < 2; ++ks) {
            #pragma unroll
            for (int i = 0; i < 4; ++i) {
                a2[mt][ks][i] = wpk2[ks * 16 + lg * 4 + i][c];
                a3[mt][ks][i] = wpk3[ks * 16 + lg * 4 + i][c];
            }
        }
    }

    // biases as packed bf16 pairs (1-op unpack per word)
    uint32_t bpk1[4][2], bpk2[4][2], bpk3[4][2];
    #pragma unroll
    for (int mt = 0; mt < 4; ++mt) {
        const int c = 16 * mt + lg * 4;
        bpk1[mt][0] = rpk(bsh[0][c], bsh[0][c + 1]);
        bpk1[mt][1] = rpk(bsh[0][c + 2], bsh[0][c + 3]);
        bpk2[mt][0] = rpk(bsh[1][c], bsh[1][c + 1]);
        bpk2[mt][1] = rpk(bsh[1][c + 2], bsh[1][c + 3]);
        bpk3[mt][0] = rpk(bsh[2][c], bsh[2][c + 1]);
        bpk3[mt][1] = rpk(bsh[2][c + 2], bsh[2][c + 3]);
    }

    // per-lane Wd4 values: cols 16*mt + lg*4 + r
    f4 wd4v[4];
    #pragma unroll
    for (int mt = 0; mt < 4; ++mt)
        wd4v[mt] = *(const f4*)&w4s[16 * mt + lg * 4];

    const int rl  = w * 16 + lr;        // block-local row of this lane
    const int it0 = half * 16;

    f4 zc0 = *(const f4*)(z + (size_t)(it0 * 64 + rl) * NL + lg * 8);
    f4 zc1 = *(const f4*)(z + (size_t)(it0 * 64 + rl) * NL + lg * 8 + 4);

    for (int it = it0; it < it0 + 16; ++it) {
        const int row = it * 64 + rl;
        const int rnext = (it0 + ((it - it0 + 1) & 15)) * 64 + rl;
        f4 zn0 = *(const f4*)(z + (size_t)rnext * NL + lg * 8);
        f4 zn1 = *(const f4*)(z + (size_t)rnext * NL + lg * 8 + 4);

        // ---- L1: B-frag from z ----
        u32x4 bh;
        bh[0] = pk_rtz(zc0[0], zc0[1]);
        bh[1] = pk_rtz(zc0[2], zc0[3]);
        bh[2] = pk_rtz(zc1[0], zc1[1]);
        bh[3] = pk_rtz(zc1[2], zc1[3]);

        f4 acc[4];
        #pragma unroll
        for (int mt = 0; mt < 4; ++mt) {
            acc[mt][0] = __uint_as_float(bpk1[mt][0] << 16);
            acc[mt][1] = __uint_as_float(bpk1[mt][0] & 0xFFFF0000u);
            acc[mt][2] = __uint_as_float(bpk1[mt][1] << 16);
            acc[mt][3] = __uint_as_float(bpk1[mt][1] & 0xFFFF0000u);
            acc[mt] = mfma16h(a1[mt], bh, acc[mt]);
        }

        // relu + pack h1
        uint32_t pk[4][2];
        #pragma unroll
        for (int mt = 0; mt < 4; ++mt) {
            pk[mt][0] = pk_rtz(fmaxf(acc[mt][0], 0.f), fmaxf(acc[mt][1], 0.f));
            pk[mt][1] = pk_rtz(fmaxf(acc[mt][2], 0.f), fmaxf(acc[mt][3], 0.f));
        }

        // ---- L2 ----
        #pragma unroll
        for (int mt = 0; mt < 4; ++mt) {
            acc[mt][0] = __uint_as_float(bpk2[mt][0] << 16);
            acc[mt][1] = __uint_as_float(bpk2[mt][0] & 0xFFFF0000u);
            acc[mt][2] = __uint_as_float(bpk2[mt][1] << 16);
            acc[mt][3] = __uint_as_float(bpk2[mt][1] & 0xFFFF0000u);
        }
        #pragma unroll
        for (int ks = 0; ks < 2; ++ks) {
            u32x4 bf;
            {
                uint32_t b0, b2, b1, b3;
                xch(pk[2 * ks][0], pk[2 * ks + 1][0], b0, b2);
                xch(pk[2 * ks][1], pk[2 * ks + 1][1], b1, b3);
                bf[0] = b0; bf[1] = b1; bf[2] = b2; bf[3] = b3;
            }
            #pragma unroll
            for (int mt = 0; mt < 4; ++mt)
                acc[mt] = mfma16h(a2[mt][ks], bf, acc[mt]);
        }

        // relu + pack h2
        uint32_t pk2_[4][2];
        #pragma unroll
        for (int mt = 0; mt < 4; ++mt) {
            pk2_[mt][0] = pk_rtz(fmaxf(acc[mt][0], 0.f), fmaxf(acc[mt][1], 0.f));
            pk2_[mt][1] = pk_rtz(fmaxf(acc[mt][2], 0.f), fmaxf(acc[mt][3], 0.f));
        }

        // ---- L3 ----
        #pragma unroll
        for (int mt = 0; mt < 4; ++mt) {
            acc[mt][0] = __uint_as_float(bpk3[mt][0] << 16);
            acc[mt][1] = __uint_as_float(bpk3[mt][0] & 0xFFFF0000u);
            acc[mt][2] = __uint_as_float(bpk3[mt][1] << 16);
            acc[mt][3] = __uint_as_float(bpk3[mt][1] & 0xFFFF0000u);
        }
        #pragma unroll
        for (int ks = 0; ks < 2; ++ks) {
            u32x4 bf;
            {
                uint32_t b0, b2, b1, b3;
                xch(pk2_[2 * ks][0], pk2_[2 * ks + 1][0], b0, b2);
                xch(pk2_[2 * ks][1], pk2_[2 * ks + 1][1], b1, b3);
                bf[0] = b0; bf[1] = b1; bf[2] = b2; bf[3] = b3;
            }
            #pragma unroll
            for (int mt = 0; mt < 4; ++mt)
                acc[mt] = mfma16h(a3[mt][ks], bf, acc[mt]);
        }

        // ---- L4: fp32 dot with wd4 ----
        float part = 0.f;
        #pragma unroll
        for (int mt = 0; mt < 4; ++mt) {
            part = fmaf(fmaxf(acc[mt][0], 0.f), wd4v[mt][0], part);
            part = fmaf(fmaxf(acc[mt][1], 0.f), wd4v[mt][1], part);
            part = fmaf(fmaxf(acc[mt][2], 0.f), wd4v[mt][2], part);
            part = fmaf(fmaxf(acc[mt][3], 0.f), wd4v[mt][3], part);
        }
        part += __shfl_xor(part, 16);
        part += __shfl_xor(part, 32);
        if ((t & 48) == 0)
            out[(size_t)row * NU + u] = part + b4;

        zc0 = zn0; zc1 = zn1;
    }
}

// ----------------------------------------------------------------- launch ---
extern "C" void kernel_launch(void* const* d_in, const int* in_sizes, int n_in,
                              void* d_out, int out_size, void* d_ws, size_t ws_size,
                              hipStream_t stream)
{
    const float* x   = (const float*)d_in[0];
    const float* We1 = (const float*)d_in[1];
    const float* be1 = (const float*)d_in[2];
    const float* We2 = (const float*)d_in[3];
    const float* be2 = (const float*)d_in[4];
    const float* We3 = (const float*)d_in[5];
    const float* be3 = (const float*)d_in[6];
    const float* We4 = (const float*)d_in[7];
    const float* be4 = (const float*)d_in[8];
    const float* Wd1 = (const float*)d_in[9];
    const float* bd1 = (const float*)d_in[10];
    const float* Wd2 = (const float*)d_in[11];
    const float* bd2 = (const float*)d_in[12];
    const float* Wd3 = (const float*)d_in[13];
    const float* bd3 = (const float*)d_in[14];
    const float* Wd4 = (const float*)d_in[15];
    const float* bd4 = (const float*)d_in[16];
    float* out = (float*)d_out;

    float* zbuf = (float*)d_ws;   // 256 KB scratch

    enc_kernel<<<NB / 8, 256, 0, stream>>>(x, We1, be1, We2, be2, We3, be3,
                                           We4, be4, zbuf);
    dec_kernel<<<NU * 2, 256, 0, stream>>>(zbuf, Wd1, bd1, Wd2, bd2,
                                           Wd3, bd3, Wd4, bd4, out);
}

// Round 8
// 61.781 us; speedup vs baseline: 2.4711x; 2.3167x over previous
//
#include <hip/hip_runtime.h>
#include <hip/hip_bf16.h>
#include <hip/hip_fp16.h>
#include <stdint.h>

#define NB 2048
#define NU 512
#define NL 32
#define NH 64

typedef float    f4    __attribute__((ext_vector_type(4)));
typedef uint32_t u32x4 __attribute__((ext_vector_type(4)));
typedef _Float16 h8    __attribute__((ext_vector_type(8)));

__device__ __forceinline__ f4 mfma16h(u32x4 a, u32x4 b, f4 c) {
    return __builtin_amdgcn_mfma_f32_16x16x32_f16(
        __builtin_bit_cast(h8, a), __builtin_bit_cast(h8, b), c, 0, 0, 0);
}

// RNE fp16 pair pack: low = h(a), high = h(b). (staging, one-time)
__device__ __forceinline__ uint32_t pk2h(float a, float b) {
    uint32_t la = (uint32_t)__half_as_ushort(__float2half_rn(a));
    uint32_t hb = (uint32_t)__half_as_ushort(__float2half_rn(b));
    return la | (hb << 16);
}

// RTZ fp16 pack (activations, 1 VALU op)
__device__ __forceinline__ uint32_t pk_rtz(float e, float o) {
    return __builtin_bit_cast(uint32_t, __builtin_amdgcn_cvt_pkrtz(e, o));
}

// bf16 pack of a pair (bias storage; 1-op unpack via shift/and)
__device__ __forceinline__ uint32_t rpk(float e, float o) {
    return __builtin_amdgcn_perm(__float_as_uint(o) + 0x8000u,
                                 __float_as_uint(e) + 0x8000u, 0x07060302u);
}

// act exchange: 4x16-lane-group block transpose via permlane swaps
__device__ __forceinline__ void xch(uint32_t A, uint32_t B,
                                    uint32_t& o0, uint32_t& o1) {
    asm("v_permlane32_swap_b32 %0, %1" : "+v"(A), "+v"(B));
    asm("v_permlane16_swap_b32 %0, %1" : "+v"(A), "+v"(B));
    o0 = A; o1 = B;
}

// ---------------------------------------------------------------- encoder ---
__global__ __launch_bounds__(256)
void enc_kernel(const float* __restrict__ x,
                const float* __restrict__ We1, const float* __restrict__ be1,
                const float* __restrict__ We2, const float* __restrict__ be2,
                const float* __restrict__ We3, const float* __restrict__ be3,
                const float* __restrict__ We4, const float* __restrict__ be4,
                float* __restrict__ z)
{
    const int RE = 8;
    __shared__ float xs[RE][512];
    __shared__ float ws[128 * 64];
    __shared__ float h[RE][NH];
    __shared__ float h2s[RE][NH];

    const int t  = threadIdx.x;
    const int r0 = blockIdx.x * RE;

    {
        const f4* xv  = (const f4*)(x + (size_t)r0 * 512);
        f4*       xsv = (f4*)&xs[0][0];
        for (int i = t; i < RE * 512 / 4; i += 256) xsv[i] = xv[i];
    }

    const int j = t & 63;
    const int w = t >> 6;

    float acc0 = be1[j], acc1 = be1[j];
    for (int kc = 0; kc < 512; kc += 128) {
        __syncthreads();
        const f4* wv  = (const f4*)(We1 + (size_t)kc * 64);
        f4*       wsv = (f4*)ws;
        for (int i = t; i < 128 * 64 / 4; i += 256) wsv[i] = wv[i];
        __syncthreads();
        #pragma unroll 8
        for (int k = 0; k < 128; ++k) {
            float wval = ws[k * 64 + j];
            acc0 = fmaf(xs[w][kc + k],     wval, acc0);
            acc1 = fmaf(xs[w + 4][kc + k], wval, acc1);
        }
    }
    acc0 = fmaxf(acc0, 0.f); acc1 = fmaxf(acc1, 0.f);
    __syncthreads();
    h[w][j] = acc0; h[w + 4][j] = acc1;
    __syncthreads();

    acc0 = be2[j]; acc1 = be2[j];
    #pragma unroll
    for (int k = 0; k < 64; ++k) {
        float wval = We2[k * 64 + j];
        acc0 = fmaf(h[w][k],     wval, acc0);
        acc1 = fmaf(h[w + 4][k], wval, acc1);
    }
    acc0 = fmaxf(acc0, 0.f); acc1 = fmaxf(acc1, 0.f);
    h2s[w][j] = acc0; h2s[w + 4][j] = acc1;
    __syncthreads();

    acc0 = be3[j]; acc1 = be3[j];
    #pragma unroll
    for (int k = 0; k < 64; ++k) {
        float wval = We3[k * 64 + j];
        acc0 = fmaf(h2s[w][k],     wval, acc0);
        acc1 = fmaf(h2s[w + 4][k], wval, acc1);
    }
    acc0 = fmaxf(acc0, 0.f); acc1 = fmaxf(acc1, 0.f);
    h[w][j] = acc0; h[w + 4][j] = acc1;
    __syncthreads();

    const int j4  = t & 31;
    const int row = t >> 5;
    float acc = be4[j4];
    #pragma unroll
    for (int k = 0; k < 64; ++k)
        acc = fmaf(h[row][k], We4[k * 32 + j4], acc);
    z[(size_t)r0 * 32 + t] = acc;
}

// ---------------------------------------------------------------- decoder ---
// 1024 blocks = 2 per unit (batch halves), 4 waves x 16 rows, 16 iters each.
//
// LDS OCCUPANCY PAD (the round-6/7 spill fix): the register allocator sets
// its VGPR budget from LDS-constrained max occupancy and IGNORES
// launch_bounds / waves_per_eu (measured: 23 KB LDS -> 7 blocks/CU target
// -> 64-VGPR budget -> 80-word frag set spilled -> 400+ MB scratch HBM
// traffic). Padding LDS to ~33.7 KB caps occupancy at 4 blocks/CU
// -> budget 512/4 = 128 VGPRs >= the ~112 this body needs (round-5 data).
template <int K2>
__device__ __forceinline__ void stageW(const float* __restrict__ g,
                                       uint32_t (*dst)[68], int t)
{
    for (int g4 = t; g4 < K2 * 16; g4 += 256) {
        const int k2 = g4 >> 4, c4 = (g4 & 15) << 2;
        f4 a = *(const f4*)(g + (size_t)(2 * k2) * NH + c4);
        f4 b = *(const f4*)(g + (size_t)(2 * k2 + 1) * NH + c4);
        u32x4 p;
        p[0] = pk2h(a[0], b[0]);
        p[1] = pk2h(a[1], b[1]);
        p[2] = pk2h(a[2], b[2]);
        p[3] = pk2h(a[3], b[3]);
        *(u32x4*)&dst[k2][c4] = p;
    }
}

__global__ __launch_bounds__(256)
void dec_kernel(const float* __restrict__ z,
                const float* __restrict__ Wd1, const float* __restrict__ bd1,
                const float* __restrict__ Wd2, const float* __restrict__ bd2,
                const float* __restrict__ Wd3, const float* __restrict__ bd3,
                const float* __restrict__ Wd4, const float* __restrict__ bd4,
                float* __restrict__ out)
{
    __shared__ uint32_t wpk1[16][68];   // fp16-pair packed W^T (pad 68: 2-way free)
    __shared__ uint32_t wpk2[32][68];
    __shared__ uint32_t wpk3[72][68];   // rows 32..71 = occupancy pad (see above)
    __shared__ float bsh[3][NH];
    __shared__ float w4s[NH];

    const int bid  = blockIdx.x;
    const int half = bid >> 9;          // batch half: iters [half*16, half*16+16)
    const int ub   = bid & 511;
    // bijective unit swizzle: 16 consecutive u (one 64B out-line) share bid%8 -> one XCD
    const int u = ((ub & 7) << 4) | (((ub >> 3) & 3) << 7) | (ub >> 5);
    const int t = threadIdx.x;

    stageW<16>(Wd1 + (size_t)u * NL * NH, wpk1, t);
    stageW<32>(Wd2 + (size_t)u * NH * NH, wpk2, t);
    stageW<32>(Wd3 + (size_t)u * NH * NH, wpk3, t);
    if (t < NH) {
        bsh[0][t] = bd1[(size_t)u * NH + t];
        bsh[1][t] = bd2[(size_t)u * NH + t];
        bsh[2][t] = bd3[(size_t)u * NH + t];
        w4s[t]    = Wd4[(size_t)u * NH + t];
    }
    __syncthreads();

    const int w  = t >> 6;          // wave 0..3
    const int lr = t & 15;          // batch-row lane
    const int lg = (t & 63) >> 4;   // lane group 0..3
    const float b4 = bd4[u];

    // ---- register A-fragments (W^T), packed fp16 pairs from LDS ----
    u32x4 a1[4], a2[4][2], a3[4][2];
    #pragma unroll
    for (int mt = 0; mt < 4; ++mt) {
        const int c = lr + 16 * mt;
        #pragma unroll
        for (int i = 0; i < 4; ++i)
            a1[mt][i] = wpk1[lg * 4 + i][c];
        #pragma unroll
        for (int ks = 0; ks < 2; ++ks) {
            #pragma unroll
            for (int i = 0; i < 4; ++i) {
                a2[mt][ks][i] = wpk2[ks * 16 + lg * 4 + i][c];
                a3[mt][ks][i] = wpk3[ks * 16 + lg * 4 + i][c];
            }
        }
    }

    // biases as packed bf16 pairs (1-op unpack per word)
    uint32_t bpk1[4][2], bpk2[4][2], bpk3[4][2];
    #pragma unroll
    for (int mt = 0; mt < 4; ++mt) {
        const int c = 16 * mt + lg * 4;
        bpk1[mt][0] = rpk(bsh[0][c], bsh[0][c + 1]);
        bpk1[mt][1] = rpk(bsh[0][c + 2], bsh[0][c + 3]);
        bpk2[mt][0] = rpk(bsh[1][c], bsh[1][c + 1]);
        bpk2[mt][1] = rpk(bsh[1][c + 2], bsh[1][c + 3]);
        bpk3[mt][0] = rpk(bsh[2][c], bsh[2][c + 1]);
        bpk3[mt][1] = rpk(bsh[2][c + 2], bsh[2][c + 3]);
    }

    // per-lane Wd4 values: cols 16*mt + lg*4 + r
    f4 wd4v[4];
    #pragma unroll
    for (int mt = 0; mt < 4; ++mt)
        wd4v[mt] = *(const f4*)&w4s[16 * mt + lg * 4];

    const int rl  = w * 16 + lr;        // block-local row of this lane
    const int it0 = half * 16;

    f4 zc0 = *(const f4*)(z + (size_t)(it0 * 64 + rl) * NL + lg * 8);
    f4 zc1 = *(const f4*)(z + (size_t)(it0 * 64 + rl) * NL + lg * 8 + 4);

    for (int it = it0; it < it0 + 16; ++it) {
        const int row = it * 64 + rl;
        const int rnext = (it0 + ((it - it0 + 1) & 15)) * 64 + rl;
        f4 zn0 = *(const f4*)(z + (size_t)rnext * NL + lg * 8);
        f4 zn1 = *(const f4*)(z + (size_t)rnext * NL + lg * 8 + 4);

        // ---- L1: B-frag from z ----
        u32x4 bh;
        bh[0] = pk_rtz(zc0[0], zc0[1]);
        bh[1] = pk_rtz(zc0[2], zc0[3]);
        bh[2] = pk_rtz(zc1[0], zc1[1]);
        bh[3] = pk_rtz(zc1[2], zc1[3]);

        f4 acc[4];
        #pragma unroll
        for (int mt = 0; mt < 4; ++mt) {
            acc[mt][0] = __uint_as_float(bpk1[mt][0] << 16);
            acc[mt][1] = __uint_as_float(bpk1[mt][0] & 0xFFFF0000u);
            acc[mt][2] = __uint_as_float(bpk1[mt][1] << 16);
            acc[mt][3] = __uint_as_float(bpk1[mt][1] & 0xFFFF0000u);
            acc[mt] = mfma16h(a1[mt], bh, acc[mt]);
        }

        // relu + pack h1
        uint32_t pk[4][2];
        #pragma unroll
        for (int mt = 0; mt < 4; ++mt) {
            pk[mt][0] = pk_rtz(fmaxf(acc[mt][0], 0.f), fmaxf(acc[mt][1], 0.f));
            pk[mt][1] = pk_rtz(fmaxf(acc[mt][2], 0.f), fmaxf(acc[mt][3], 0.f));
        }

        // ---- L2 ----
        #pragma unroll
        for (int mt = 0; mt < 4; ++mt) {
            acc[mt][0] = __uint_as_float(bpk2[mt][0] << 16);
            acc[mt][1] = __uint_as_float(bpk2[mt][0] & 0xFFFF0000u);
            acc[mt][2] = __uint_as_float(bpk2[mt][1] << 16);
            acc[mt][3] = __uint_as_float(bpk2[mt][1] & 0xFFFF0000u);
        }
        #pragma unroll
        for (int ks = 0; ks < 2; ++ks) {
            u32x4 bf;
            {
                uint32_t b0, b2, b1, b3;
                xch(pk[2 * ks][0], pk[2 * ks + 1][0], b0, b2);
                xch(pk[2 * ks][1], pk[2 * ks + 1][1], b1, b3);
                bf[0] = b0; bf[1] = b1; bf[2] = b2; bf[3] = b3;
            }
            #pragma unroll
            for (int mt = 0; mt < 4; ++mt)
                acc[mt] = mfma16h(a2[mt][ks], bf, acc[mt]);
        }

        // relu + pack h2
        uint32_t pk2_[4][2];
        #pragma unroll
        for (int mt = 0; mt < 4; ++mt) {
            pk2_[mt][0] = pk_rtz(fmaxf(acc[mt][0], 0.f), fmaxf(acc[mt][1], 0.f));
            pk2_[mt][1] = pk_rtz(fmaxf(acc[mt][2], 0.f), fmaxf(acc[mt][3], 0.f));
        }

        // ---- L3 ----
        #pragma unroll
        for (int mt = 0; mt < 4; ++mt) {
            acc[mt][0] = __uint_as_float(bpk3[mt][0] << 16);
            acc[mt][1] = __uint_as_float(bpk3[mt][0] & 0xFFFF0000u);
            acc[mt][2] = __uint_as_float(bpk3[mt][1] << 16);
            acc[mt][3] = __uint_as_float(bpk3[mt][1] & 0xFFFF0000u);
        }
        #pragma unroll
        for (int ks = 0; ks < 2; ++ks) {
            u32x4 bf;
            {
                uint32_t b0, b2, b1, b3;
                xch(pk2_[2 * ks][0], pk2_[2 * ks + 1][0], b0, b2);
                xch(pk2_[2 * ks][1], pk2_[2 * ks + 1][1], b1, b3);
                bf[0] = b0; bf[1] = b1; bf[2] = b2; bf[3] = b3;
            }
            #pragma unroll
            for (int mt = 0; mt < 4; ++mt)
                acc[mt] = mfma16h(a3[mt][ks], bf, acc[mt]);
        }

        // ---- L4: fp32 dot with wd4 ----
        float part = 0.f;
        #pragma unroll
        for (int mt = 0; mt < 4; ++mt) {
            part = fmaf(fmaxf(acc[mt][0], 0.f), wd4v[mt][0], part);
            part = fmaf(fmaxf(acc[mt][1], 0.f), wd4v[mt][1], part);
            part = fmaf(fmaxf(acc[mt][2], 0.f), wd4v[mt][2], part);
            part = fmaf(fmaxf(acc[mt][3], 0.f), wd4v[mt][3], part);
        }
        part += __shfl_xor(part, 16);
        part += __shfl_xor(part, 32);
        if ((t & 48) == 0)
            out[(size_t)row * NU + u] = part + b4;

        zc0 = zn0; zc1 = zn1;
    }
}

// ----------------------------------------------------------------- launch ---
extern "C" void kernel_launch(void* const* d_in, const int* in_sizes, int n_in,
                              void* d_out, int out_size, void* d_ws, size_t ws_size,
                              hipStream_t stream)
{
    const float* x   = (const float*)d_in[0];
    const float* We1 = (const float*)d_in[1];
    const float* be1 = (const float*)d_in[2];
    const float* We2 = (const float*)d_in[3];
    const float* be2 = (const float*)d_in[4];
    const float* We3 = (const float*)d_in[5];
    const float* be3 = (const float*)d_in[6];
    const float* We4 = (const float*)d_in[7];
    const float* be4 = (const float*)d_in[8];
    const float* Wd1 = (const float*)d_in[9];
    const float* bd1 = (const float*)d_in[10];
    const float* Wd2 = (const float*)d_in[11];
    const float* bd2 = (const float*)d_in[12];
    const float* Wd3 = (const float*)d_in[13];
    const float* bd3 = (const float*)d_in[14];
    const float* Wd4 = (const float*)d_in[15];
    const float* bd4 = (const float*)d_in[16];
    float* out = (float*)d_out;

    float* zbuf = (float*)d_ws;   // 256 KB scratch

    enc_kernel<<<NB / 8, 256, 0, stream>>>(x, We1, be1, We2, be2, We3, be3,
                                           We4, be4, zbuf);
    dec_kernel<<<NU * 2, 256, 0, stream>>>(zbuf, Wd1, bd1, Wd2, bd2,
                                           Wd3, bd3, Wd4, bd4, out);
}

// Round 9
// 56.630 us; speedup vs baseline: 2.6959x; 1.0910x over previous
//
#include <hip/hip_runtime.h>
#include <hip/hip_bf16.h>
#include <hip/hip_fp16.h>
#include <stdint.h>

#define NB 2048
#define NU 512
#define NL 32
#define NH 64

typedef float    f4    __attribute__((ext_vector_type(4)));
typedef uint32_t u32x4 __attribute__((ext_vector_type(4)));
typedef _Float16 h8    __attribute__((ext_vector_type(8)));

__device__ __forceinline__ f4 mfma16h(u32x4 a, u32x4 b, f4 c) {
    return __builtin_amdgcn_mfma_f32_16x16x32_f16(
        __builtin_bit_cast(h8, a), __builtin_bit_cast(h8, b), c, 0, 0, 0);
}

// RNE fp16 pair pack (staging, one-time)
__device__ __forceinline__ uint32_t pk2h(float a, float b) {
    uint32_t la = (uint32_t)__half_as_ushort(__float2half_rn(a));
    uint32_t hb = (uint32_t)__half_as_ushort(__float2half_rn(b));
    return la | (hb << 16);
}

// RTZ fp16 pack (activations, 1 VALU op)
__device__ __forceinline__ uint32_t pk_rtz(float e, float o) {
    return __builtin_bit_cast(uint32_t, __builtin_amdgcn_cvt_pkrtz(e, o));
}

// pack + relu in 2 ops: cvt_pkrtz then packed max with 0
// (identical to fmax-then-cvt: negatives -> +0, positives unchanged)
__device__ __forceinline__ uint32_t pk_relu(float e, float o) {
    uint32_t r = pk_rtz(e, o);
    asm("v_pk_max_f16 %0, %1, 0" : "=v"(r) : "v"(r));
    return r;
}

// act exchange: 4x16-lane-group block transpose via permlane swaps
__device__ __forceinline__ void xch(uint32_t A, uint32_t B,
                                    uint32_t& o0, uint32_t& o1) {
    asm("v_permlane32_swap_b32 %0, %1" : "+v"(A), "+v"(B));
    asm("v_permlane16_swap_b32 %0, %1" : "+v"(A), "+v"(B));
    o0 = A; o1 = B;
}

// ---------------------------------------------------------------- encoder ---
__global__ __launch_bounds__(256)
void enc_kernel(const float* __restrict__ x,
                const float* __restrict__ We1, const float* __restrict__ be1,
                const float* __restrict__ We2, const float* __restrict__ be2,
                const float* __restrict__ We3, const float* __restrict__ be3,
                const float* __restrict__ We4, const float* __restrict__ be4,
                float* __restrict__ z)
{
    const int RE = 8;
    __shared__ float xs[RE][512];
    __shared__ float ws[128 * 64];
    __shared__ float h[RE][NH];
    __shared__ float h2s[RE][NH];

    const int t  = threadIdx.x;
    const int r0 = blockIdx.x * RE;

    {
        const f4* xv  = (const f4*)(x + (size_t)r0 * 512);
        f4*       xsv = (f4*)&xs[0][0];
        for (int i = t; i < RE * 512 / 4; i += 256) xsv[i] = xv[i];
    }

    const int j = t & 63;
    const int w = t >> 6;

    float acc0 = be1[j], acc1 = be1[j];
    for (int kc = 0; kc < 512; kc += 128) {
        __syncthreads();
        const f4* wv  = (const f4*)(We1 + (size_t)kc * 64);
        f4*       wsv = (f4*)ws;
        for (int i = t; i < 128 * 64 / 4; i += 256) wsv[i] = wv[i];
        __syncthreads();
        #pragma unroll 8
        for (int k = 0; k < 128; ++k) {
            float wval = ws[k * 64 + j];
            acc0 = fmaf(xs[w][kc + k],     wval, acc0);
            acc1 = fmaf(xs[w + 4][kc + k], wval, acc1);
        }
    }
    acc0 = fmaxf(acc0, 0.f); acc1 = fmaxf(acc1, 0.f);
    __syncthreads();
    h[w][j] = acc0; h[w + 4][j] = acc1;
    __syncthreads();

    acc0 = be2[j]; acc1 = be2[j];
    #pragma unroll
    for (int k = 0; k < 64; ++k) {
        float wval = We2[k * 64 + j];
        acc0 = fmaf(h[w][k],     wval, acc0);
        acc1 = fmaf(h[w + 4][k], wval, acc1);
    }
    acc0 = fmaxf(acc0, 0.f); acc1 = fmaxf(acc1, 0.f);
    h2s[w][j] = acc0; h2s[w + 4][j] = acc1;
    __syncthreads();

    acc0 = be3[j]; acc1 = be3[j];
    #pragma unroll
    for (int k = 0; k < 64; ++k) {
        float wval = We3[k * 64 + j];
        acc0 = fmaf(h2s[w][k],     wval, acc0);
        acc1 = fmaf(h2s[w + 4][k], wval, acc1);
    }
    acc0 = fmaxf(acc0, 0.f); acc1 = fmaxf(acc1, 0.f);
    h[w][j] = acc0; h[w + 4][j] = acc1;
    __syncthreads();

    const int j4  = t & 31;
    const int row = t >> 5;
    float acc = be4[j4];
    #pragma unroll
    for (int k = 0; k < 64; ++k)
        acc = fmaf(h[row][k], We4[k * 32 + j4], acc);
    z[(size_t)r0 * 32 + t] = acc;
}

// ---------------------------------------------------------------- decoder ---
// 512 blocks (1/unit), 4 waves x 16 rows, 32 iters.
//
// Measured law (r5..r8): per-wave-iteration cost is issue-saturated at
// ~const SIMD-cycles; occupancy beyond 8 waves/CU buys nothing. So this
// round CUTS per-iter instructions instead:
//  - bias C-quads live in 48 loop-invariant VGPRs, fed to MFMA's C operand
//    directly (removes 48 unpack ops/iter)
//  - relu fused into pack via v_pk_max_f16 (removes 16 ops/iter)
// The 48 extra regs need budget > 128, so LDS is padded to 54.9 KB ->
// 2 blocks/CU target -> RA budget 256 (the r6-r8 allocator law, now used
// deliberately). Occupancy 8 waves/CU -- proven equivalent to 16.
template <int K2>
__device__ __forceinline__ void stageW(const float* __restrict__ g,
                                       uint32_t (*dst)[68], int t)
{
    for (int g4 = t; g4 < K2 * 16; g4 += 256) {
        const int k2 = g4 >> 4, c4 = (g4 & 15) << 2;
        f4 a = *(const f4*)(g + (size_t)(2 * k2) * NH + c4);
        f4 b = *(const f4*)(g + (size_t)(2 * k2 + 1) * NH + c4);
        u32x4 p;
        p[0] = pk2h(a[0], b[0]);
        p[1] = pk2h(a[1], b[1]);
        p[2] = pk2h(a[2], b[2]);
        p[3] = pk2h(a[3], b[3]);
        *(u32x4*)&dst[k2][c4] = p;
    }
}

__global__ __launch_bounds__(256)
void dec_kernel(const float* __restrict__ z,
                const float* __restrict__ Wd1, const float* __restrict__ bd1,
                const float* __restrict__ Wd2, const float* __restrict__ bd2,
                const float* __restrict__ Wd3, const float* __restrict__ bd3,
                const float* __restrict__ Wd4, const float* __restrict__ bd4,
                float* __restrict__ out)
{
    __shared__ uint32_t wpk1[16][68];    // fp16-pair packed W^T
    __shared__ uint32_t wpk2[32][68];
    __shared__ uint32_t wpk3[150][68];   // rows 32..149 = occupancy pad (see above)
    __shared__ float bsh[3][NH];
    __shared__ float w4s[NH];

    const int bid = blockIdx.x;
    // bijective unit swizzle: 16 consecutive u (one 64B out-line) share bid%8 -> one XCD
    const int u = ((bid & 7) << 4) | (((bid >> 3) & 3) << 7) | (bid >> 5);
    const int t = threadIdx.x;

    stageW<16>(Wd1 + (size_t)u * NL * NH, wpk1, t);
    stageW<32>(Wd2 + (size_t)u * NH * NH, wpk2, t);
    stageW<32>(Wd3 + (size_t)u * NH * NH, wpk3, t);
    if (t < NH) {
        bsh[0][t] = bd1[(size_t)u * NH + t];
        bsh[1][t] = bd2[(size_t)u * NH + t];
        bsh[2][t] = bd3[(size_t)u * NH + t];
        w4s[t]    = Wd4[(size_t)u * NH + t];
    }
    __syncthreads();

    const int w  = t >> 6;          // wave 0..3
    const int lr = t & 15;          // batch-row lane
    const int lg = (t & 63) >> 4;   // lane group 0..3
    const float b4 = bd4[u];

    // ---- register A-fragments (W^T), packed fp16 pairs from LDS ----
    u32x4 a1[4], a2[4][2], a3[4][2];
    #pragma unroll
    for (int mt = 0; mt < 4; ++mt) {
        const int c = lr + 16 * mt;
        #pragma unroll
        for (int i = 0; i < 4; ++i)
            a1[mt][i] = wpk1[lg * 4 + i][c];
        #pragma unroll
        for (int ks = 0; ks < 2; ++ks) {
            #pragma unroll
            for (int i = 0; i < 4; ++i) {
                a2[mt][ks][i] = wpk2[ks * 16 + lg * 4 + i][c];
                a3[mt][ks][i] = wpk3[ks * 16 + lg * 4 + i][c];
            }
        }
    }

    // ---- loop-invariant bias C-quads (row = 16*mt + lg*4 + r), 48 VGPRs ----
    f4 bc1[4], bc2[4], bc3[4];
    #pragma unroll
    for (int mt = 0; mt < 4; ++mt) {
        bc1[mt] = *(const f4*)&bsh[0][16 * mt + lg * 4];
        bc2[mt] = *(const f4*)&bsh[1][16 * mt + lg * 4];
        bc3[mt] = *(const f4*)&bsh[2][16 * mt + lg * 4];
    }

    // per-lane Wd4 values: cols 16*mt + lg*4 + r
    f4 wd4v[4];
    #pragma unroll
    for (int mt = 0; mt < 4; ++mt)
        wd4v[mt] = *(const f4*)&w4s[16 * mt + lg * 4];

    const int rl = w * 16 + lr;     // block-local row of this lane

    f4 zc0 = *(const f4*)(z + (size_t)rl * NL + lg * 8);
    f4 zc1 = *(const f4*)(z + (size_t)rl * NL + lg * 8 + 4);

    for (int it = 0; it < 32; ++it) {
        const int row = it * 64 + rl;
        const int rnext = ((it + 1) & 31) * 64 + rl;
        f4 zn0 = *(const f4*)(z + (size_t)rnext * NL + lg * 8);
        f4 zn1 = *(const f4*)(z + (size_t)rnext * NL + lg * 8 + 4);

        // ---- L1: B-frag from z; C = resident bias ----
        u32x4 bh;
        bh[0] = pk_rtz(zc0[0], zc0[1]);
        bh[1] = pk_rtz(zc0[2], zc0[3]);
        bh[2] = pk_rtz(zc1[0], zc1[1]);
        bh[3] = pk_rtz(zc1[2], zc1[3]);

        f4 acc[4];
        #pragma unroll
        for (int mt = 0; mt < 4; ++mt)
            acc[mt] = mfma16h(a1[mt], bh, bc1[mt]);

        // relu + pack h1 (2 ops per word)
        uint32_t pk[4][2];
        #pragma unroll
        for (int mt = 0; mt < 4; ++mt) {
            pk[mt][0] = pk_relu(acc[mt][0], acc[mt][1]);
            pk[mt][1] = pk_relu(acc[mt][2], acc[mt][3]);
        }

        // ---- L2: C = resident bias on ks=0, chain on ks=1 ----
        {
            u32x4 bf;
            uint32_t b0, b2, b1, b3;
            xch(pk[0][0], pk[1][0], b0, b2);
            xch(pk[0][1], pk[1][1], b1, b3);
            bf[0] = b0; bf[1] = b1; bf[2] = b2; bf[3] = b3;
            #pragma unroll
            for (int mt = 0; mt < 4; ++mt)
                acc[mt] = mfma16h(a2[mt][0], bf, bc2[mt]);
        }
        {
            u32x4 bf;
            uint32_t b0, b2, b1, b3;
            xch(pk[2][0], pk[3][0], b0, b2);
            xch(pk[2][1], pk[3][1], b1, b3);
            bf[0] = b0; bf[1] = b1; bf[2] = b2; bf[3] = b3;
            #pragma unroll
            for (int mt = 0; mt < 4; ++mt)
                acc[mt] = mfma16h(a2[mt][1], bf, acc[mt]);
        }

        // relu + pack h2
        uint32_t pk2_[4][2];
        #pragma unroll
        for (int mt = 0; mt < 4; ++mt) {
            pk2_[mt][0] = pk_relu(acc[mt][0], acc[mt][1]);
            pk2_[mt][1] = pk_relu(acc[mt][2], acc[mt][3]);
        }

        // ---- L3 ----
        {
            u32x4 bf;
            uint32_t b0, b2, b1, b3;
            xch(pk2_[0][0], pk2_[1][0], b0, b2);
            xch(pk2_[0][1], pk2_[1][1], b1, b3);
            bf[0] = b0; bf[1] = b1; bf[2] = b2; bf[3] = b3;
            #pragma unroll
            for (int mt = 0; mt < 4; ++mt)
                acc[mt] = mfma16h(a3[mt][0], bf, bc3[mt]);
        }
        {
            u32x4 bf;
            uint32_t b0, b2, b1, b3;
            xch(pk2_[2][0], pk2_[3][0], b0, b2);
            xch(pk2_[2][1], pk2_[3][1], b1, b3);
            bf[0] = b0; bf[1] = b1; bf[2] = b2; bf[3] = b3;
            #pragma unroll
            for (int mt = 0; mt < 4; ++mt)
                acc[mt] = mfma16h(a3[mt][1], bf, acc[mt]);
        }

        // ---- L4: fp32 dot with wd4 ----
        float part = 0.f;
        #pragma unroll
        for (int mt = 0; mt < 4; ++mt) {
            part = fmaf(fmaxf(acc[mt][0], 0.f), wd4v[mt][0], part);
            part = fmaf(fmaxf(acc[mt][1], 0.f), wd4v[mt][1], part);
            part = fmaf(fmaxf(acc[mt][2], 0.f), wd4v[mt][2], part);
            part = fmaf(fmaxf(acc[mt][3], 0.f), wd4v[mt][3], part);
        }
        part += __shfl_xor(part, 16);
        part += __shfl_xor(part, 32);
        if ((t & 48) == 0)
            out[(size_t)row * NU + u] = part + b4;

        zc0 = zn0; zc1 = zn1;
    }
}

// ----------------------------------------------------------------- launch ---
extern "C" void kernel_launch(void* const* d_in, const int* in_sizes, int n_in,
                              void* d_out, int out_size, void* d_ws, size_t ws_size,
                              hipStream_t stream)
{
    const float* x   = (const float*)d_in[0];
    const float* We1 = (const float*)d_in[1];
    const float* be1 = (const float*)d_in[2];
    const float* We2 = (const float*)d_in[3];
    const float* be2 = (const float*)d_in[4];
    const float* We3 = (const float*)d_in[5];
    const float* be3 = (const float*)d_in[6];
    const float* We4 = (const float*)d_in[7];
    const float* be4 = (const float*)d_in[8];
    const float* Wd1 = (const float*)d_in[9];
    const float* bd1 = (const float*)d_in[10];
    const float* Wd2 = (const float*)d_in[11];
    const float* bd2 = (const float*)d_in[12];
    const float* Wd3 = (const float*)d_in[13];
    const float* bd3 = (const float*)d_in[14];
    const float* Wd4 = (const float*)d_in[15];
    const float* bd4 = (const float*)d_in[16];
    float* out = (float*)d_out;

    float* zbuf = (float*)d_ws;   // 256 KB scratch

    enc_kernel<<<NB / 8, 256, 0, stream>>>(x, We1, be1, We2, be2, We3, be3,
                                           We4, be4, zbuf);
    dec_kernel<<<NU, 256, 0, stream>>>(zbuf, Wd1, bd1, Wd2, bd2,
                                       Wd3, bd3, Wd4, bd4, out);
}

// Round 10
// 56.265 us; speedup vs baseline: 2.7134x; 1.0065x over previous
//
#include <hip/hip_runtime.h>
#include <hip/hip_bf16.h>
#include <hip/hip_fp16.h>
#include <stdint.h>

#define NB 2048
#define NU 512
#define NL 32
#define NH 64

typedef float    f4    __attribute__((ext_vector_type(4)));
typedef uint32_t u32x4 __attribute__((ext_vector_type(4)));
typedef _Float16 h8    __attribute__((ext_vector_type(8)));
typedef _Float16 h2    __attribute__((ext_vector_type(2)));

__device__ __forceinline__ f4 mfma16h(u32x4 a, u32x4 b, f4 c) {
    return __builtin_amdgcn_mfma_f32_16x16x32_f16(
        __builtin_bit_cast(h8, a), __builtin_bit_cast(h8, b), c, 0, 0, 0);
}

// RNE fp16 pair pack (staging / encoder, one-time per value)
__device__ __forceinline__ uint32_t pk2h(float a, float b) {
    uint32_t la = (uint32_t)__half_as_ushort(__float2half_rn(a));
    uint32_t hb = (uint32_t)__half_as_ushort(__float2half_rn(b));
    return la | (hb << 16);
}

// RTZ fp16 pack (activations, 1 VALU op)
__device__ __forceinline__ uint32_t pk_rtz(float e, float o) {
    return __builtin_bit_cast(uint32_t, __builtin_amdgcn_cvt_pkrtz(e, o));
}

// pack + relu in 2 ops (identical to fmax-then-cvt)
__device__ __forceinline__ uint32_t pk_relu(float e, float o) {
    uint32_t r = pk_rtz(e, o);
    asm("v_pk_max_f16 %0, %1, 0" : "=v"(r) : "v"(r));
    return r;
}

// packed fp16 dot2 with f32 accumulate: c += a.x*b.x + a.y*b.y
__device__ __forceinline__ float dot2(uint32_t a, uint32_t b, float c) {
    return __builtin_amdgcn_fdot2(__builtin_bit_cast(h2, a),
                                  __builtin_bit_cast(h2, b), c, false);
}

// act exchange: 4x16-lane-group block transpose via permlane swaps
__device__ __forceinline__ void xch(uint32_t A, uint32_t B,
                                    uint32_t& o0, uint32_t& o1) {
    asm("v_permlane32_swap_b32 %0, %1" : "+v"(A), "+v"(B));
    asm("v_permlane16_swap_b32 %0, %1" : "+v"(A), "+v"(B));
    o0 = A; o1 = B;
}

// ---------------------------------------------------------------- encoder ---
// writes z pre-packed as fp16 pairs: zpk[row][c2] = pk2h(z[2c2], z[2c2+1])
__global__ __launch_bounds__(256)
void enc_kernel(const float* __restrict__ x,
                const float* __restrict__ We1, const float* __restrict__ be1,
                const float* __restrict__ We2, const float* __restrict__ be2,
                const float* __restrict__ We3, const float* __restrict__ be3,
                const float* __restrict__ We4, const float* __restrict__ be4,
                uint32_t* __restrict__ zpk)
{
    const int RE = 8;
    __shared__ float xs[RE][512];
    __shared__ float ws[128 * 64];
    __shared__ float h[RE][NH];
    __shared__ float h2s[RE][NH];

    const int t  = threadIdx.x;
    const int r0 = blockIdx.x * RE;

    {
        const f4* xv  = (const f4*)(x + (size_t)r0 * 512);
        f4*       xsv = (f4*)&xs[0][0];
        for (int i = t; i < RE * 512 / 4; i += 256) xsv[i] = xv[i];
    }

    const int j = t & 63;
    const int w = t >> 6;

    float acc0 = be1[j], acc1 = be1[j];
    for (int kc = 0; kc < 512; kc += 128) {
        __syncthreads();
        const f4* wv  = (const f4*)(We1 + (size_t)kc * 64);
        f4*       wsv = (f4*)ws;
        for (int i = t; i < 128 * 64 / 4; i += 256) wsv[i] = wv[i];
        __syncthreads();
        #pragma unroll 8
        for (int k = 0; k < 128; ++k) {
            float wval = ws[k * 64 + j];
            acc0 = fmaf(xs[w][kc + k],     wval, acc0);
            acc1 = fmaf(xs[w + 4][kc + k], wval, acc1);
        }
    }
    acc0 = fmaxf(acc0, 0.f); acc1 = fmaxf(acc1, 0.f);
    __syncthreads();
    h[w][j] = acc0; h[w + 4][j] = acc1;
    __syncthreads();

    acc0 = be2[j]; acc1 = be2[j];
    #pragma unroll
    for (int k = 0; k < 64; ++k) {
        float wval = We2[k * 64 + j];
        acc0 = fmaf(h[w][k],     wval, acc0);
        acc1 = fmaf(h[w + 4][k], wval, acc1);
    }
    acc0 = fmaxf(acc0, 0.f); acc1 = fmaxf(acc1, 0.f);
    h2s[w][j] = acc0; h2s[w + 4][j] = acc1;
    __syncthreads();

    acc0 = be3[j]; acc1 = be3[j];
    #pragma unroll
    for (int k = 0; k < 64; ++k) {
        float wval = We3[k * 64 + j];
        acc0 = fmaf(h2s[w][k],     wval, acc0);
        acc1 = fmaf(h2s[w + 4][k], wval, acc1);
    }
    acc0 = fmaxf(acc0, 0.f); acc1 = fmaxf(acc1, 0.f);
    h[w][j] = acc0; h[w + 4][j] = acc1;
    __syncthreads();

    const int j4  = t & 31;
    const int row = t >> 5;
    float acc = be4[j4];
    #pragma unroll
    for (int k = 0; k < 64; ++k)
        acc = fmaf(h[row][k], We4[k * 32 + j4], acc);
    // pair with odd-column neighbor, even lanes write packed word
    float nb = __shfl_xor(acc, 1);
    if ((j4 & 1) == 0)
        zpk[(size_t)(r0 + row) * 16 + (j4 >> 1)] = pk2h(acc, nb);
}

// ---------------------------------------------------------------- decoder ---
// 1024 blocks = 2/unit (batch halves), 4 waves x 16 rows, 16 iters.
// Lean r9 body (bias-C resident, pk_relu, permlane xch, packed-z B-frags,
// dot2 L4) at 4 waves/SIMD: LDS padded to 33.7 KB -> 4 blocks/CU target ->
// RA budget 128 >= the ~100 VGPR this body needs (r9 measured; r6-r8
// allocator law: budget = 512 / LDS-constrained waves-per-EU).
template <int K2>
__device__ __forceinline__ void stageW(const float* __restrict__ g,
                                       uint32_t (*dst)[68], int t)
{
    for (int g4 = t; g4 < K2 * 16; g4 += 256) {
        const int k2 = g4 >> 4, c4 = (g4 & 15) << 2;
        f4 a = *(const f4*)(g + (size_t)(2 * k2) * NH + c4);
        f4 b = *(const f4*)(g + (size_t)(2 * k2 + 1) * NH + c4);
        u32x4 p;
        p[0] = pk2h(a[0], b[0]);
        p[1] = pk2h(a[1], b[1]);
        p[2] = pk2h(a[2], b[2]);
        p[3] = pk2h(a[3], b[3]);
        *(u32x4*)&dst[k2][c4] = p;
    }
}

__global__ __launch_bounds__(256)
void dec_kernel(const uint32_t* __restrict__ zpk,
                const float* __restrict__ Wd1, const float* __restrict__ bd1,
                const float* __restrict__ Wd2, const float* __restrict__ bd2,
                const float* __restrict__ Wd3, const float* __restrict__ bd3,
                const float* __restrict__ Wd4, const float* __restrict__ bd4,
                float* __restrict__ out)
{
    __shared__ uint32_t wpk1[16][68];   // fp16-pair packed W^T
    __shared__ uint32_t wpk2[32][68];
    __shared__ uint32_t wpk3[72][68];   // rows 32..71 = occupancy pad (see above)
    __shared__ float bsh[3][NH];
    __shared__ float w4s[NH];

    const int bid  = blockIdx.x;
    const int half = bid >> 9;          // batch half: iters [half*16, half*16+16)
    const int ub   = bid & 511;
    // bijective unit swizzle: 16 consecutive u (one 64B out-line) share bid%8 -> one XCD
    const int u = ((ub & 7) << 4) | (((ub >> 3) & 3) << 7) | (ub >> 5);
    const int t = threadIdx.x;

    stageW<16>(Wd1 + (size_t)u * NL * NH, wpk1, t);
    stageW<32>(Wd2 + (size_t)u * NH * NH, wpk2, t);
    stageW<32>(Wd3 + (size_t)u * NH * NH, wpk3, t);
    if (t < NH) {
        bsh[0][t] = bd1[(size_t)u * NH + t];
        bsh[1][t] = bd2[(size_t)u * NH + t];
        bsh[2][t] = bd3[(size_t)u * NH + t];
        w4s[t]    = Wd4[(size_t)u * NH + t];
    }
    __syncthreads();

    const int w  = t >> 6;          // wave 0..3
    const int lr = t & 15;          // batch-row lane
    const int lg = (t & 63) >> 4;   // lane group 0..3
    const float b4 = bd4[u];

    // ---- register A-fragments (W^T), packed fp16 pairs from LDS ----
    u32x4 a1[4], a2[4][2], a3[4][2];
    #pragma unroll
    for (int mt = 0; mt < 4; ++mt) {
        const int c = lr + 16 * mt;
        #pragma unroll
        for (int i = 0; i < 4; ++i)
            a1[mt][i] = wpk1[lg * 4 + i][c];
        #pragma unroll
        for (int ks = 0; ks < 2; ++ks) {
            #pragma unroll
            for (int i = 0; i < 4; ++i) {
                a2[mt][ks][i] = wpk2[ks * 16 + lg * 4 + i][c];
                a3[mt][ks][i] = wpk3[ks * 16 + lg * 4 + i][c];
            }
        }
    }

    // ---- loop-invariant bias C-quads (row = 16*mt + lg*4 + r) ----
    f4 bc1[4], bc2[4], bc3[4];
    #pragma unroll
    for (int mt = 0; mt < 4; ++mt) {
        bc1[mt] = *(const f4*)&bsh[0][16 * mt + lg * 4];
        bc2[mt] = *(const f4*)&bsh[1][16 * mt + lg * 4];
        bc3[mt] = *(const f4*)&bsh[2][16 * mt + lg * 4];
    }

    // packed wd4 (fp16 RNE), cols 16*mt + lg*4 .. +3
    uint32_t wd4pk[4][2];
    #pragma unroll
    for (int mt = 0; mt < 4; ++mt) {
        const int c = 16 * mt + lg * 4;
        wd4pk[mt][0] = pk2h(w4s[c],     w4s[c + 1]);
        wd4pk[mt][1] = pk2h(w4s[c + 2], w4s[c + 3]);
    }

    const int rl  = w * 16 + lr;        // block-local row of this lane
    const int it0 = half * 16;

    // z: pre-packed fp16 pairs, one 16B load = the L1 B-frag
    u32x4 zc = *(const u32x4*)(zpk + (size_t)(it0 * 64 + rl) * 16 + lg * 4);

    for (int it = it0; it < it0 + 16; ++it) {
        const int row = it * 64 + rl;
        const int rnext = (it0 + ((it - it0 + 1) & 15)) * 64 + rl;
        u32x4 zn = *(const u32x4*)(zpk + (size_t)rnext * 16 + lg * 4);

        // ---- L1: B = packed z directly; C = resident bias ----
        f4 acc[4];
        #pragma unroll
        for (int mt = 0; mt < 4; ++mt)
            acc[mt] = mfma16h(a1[mt], zc, bc1[mt]);

        // relu + pack h1
        uint32_t pk[4][2];
        #pragma unroll
        for (int mt = 0; mt < 4; ++mt) {
            pk[mt][0] = pk_relu(acc[mt][0], acc[mt][1]);
            pk[mt][1] = pk_relu(acc[mt][2], acc[mt][3]);
        }

        // ---- L2 ----
        {
            u32x4 bf;
            uint32_t b0, b2, b1, b3;
            xch(pk[0][0], pk[1][0], b0, b2);
            xch(pk[0][1], pk[1][1], b1, b3);
            bf[0] = b0; bf[1] = b1; bf[2] = b2; bf[3] = b3;
            #pragma unroll
            for (int mt = 0; mt < 4; ++mt)
                acc[mt] = mfma16h(a2[mt][0], bf, bc2[mt]);
        }
        {
            u32x4 bf;
            uint32_t b0, b2, b1, b3;
            xch(pk[2][0], pk[3][0], b0, b2);
            xch(pk[2][1], pk[3][1], b1, b3);
            bf[0] = b0; bf[1] = b1; bf[2] = b2; bf[3] = b3;
            #pragma unroll
            for (int mt = 0; mt < 4; ++mt)
                acc[mt] = mfma16h(a2[mt][1], bf, acc[mt]);
        }

        // relu + pack h2
        uint32_t pk2_[4][2];
        #pragma unroll
        for (int mt = 0; mt < 4; ++mt) {
            pk2_[mt][0] = pk_relu(acc[mt][0], acc[mt][1]);
            pk2_[mt][1] = pk_relu(acc[mt][2], acc[mt][3]);
        }

        // ---- L3 ----
        {
            u32x4 bf;
            uint32_t b0, b2, b1, b3;
            xch(pk2_[0][0], pk2_[1][0], b0, b2);
            xch(pk2_[0][1], pk2_[1][1], b1, b3);
            bf[0] = b0; bf[1] = b1; bf[2] = b2; bf[3] = b3;
            #pragma unroll
            for (int mt = 0; mt < 4; ++mt)
                acc[mt] = mfma16h(a3[mt][0], bf, bc3[mt]);
        }
        {
            u32x4 bf;
            uint32_t b0, b2, b1, b3;
            xch(pk2_[2][0], pk2_[3][0], b0, b2);
            xch(pk2_[2][1], pk2_[3][1], b1, b3);
            bf[0] = b0; bf[1] = b1; bf[2] = b2; bf[3] = b3;
            #pragma unroll
            for (int mt = 0; mt < 4; ++mt)
                acc[mt] = mfma16h(a3[mt][1], bf, acc[mt]);
        }

        // ---- L4: pack-relu h3 + packed fp16 dot2 ----
        float part = 0.f;
        #pragma unroll
        for (int mt = 0; mt < 4; ++mt) {
            uint32_t p0 = pk_relu(acc[mt][0], acc[mt][1]);
            uint32_t p1 = pk_relu(acc[mt][2], acc[mt][3]);
            part = dot2(p0, wd4pk[mt][0], part);
            part = dot2(p1, wd4pk[mt][1], part);
        }
        part += __shfl_xor(part, 16);
        part += __shfl_xor(part, 32);
        if ((t & 48) == 0)
            out[(size_t)row * NU + u] = part + b4;

        zc = zn;
    }
}

// ----------------------------------------------------------------- launch ---
extern "C" void kernel_launch(void* const* d_in, const int* in_sizes, int n_in,
                              void* d_out, int out_size, void* d_ws, size_t ws_size,
                              hipStream_t stream)
{
    const float* x   = (const float*)d_in[0];
    const float* We1 = (const float*)d_in[1];
    const float* be1 = (const float*)d_in[2];
    const float* We2 = (const float*)d_in[3];
    const float* be2 = (const float*)d_in[4];
    const float* We3 = (const float*)d_in[5];
    const float* be3 = (const float*)d_in[6];
    const float* We4 = (const float*)d_in[7];
    const float* be4 = (const float*)d_in[8];
    const float* Wd1 = (const float*)d_in[9];
    const float* bd1 = (const float*)d_in[10];
    const float* Wd2 = (const float*)d_in[11];
    const float* bd2 = (const float*)d_in[12];
    const float* Wd3 = (const float*)d_in[13];
    const float* bd3 = (const float*)d_in[14];
    const float* Wd4 = (const float*)d_in[15];
    const float* bd4 = (const float*)d_in[16];
    float* out = (float*)d_out;

    uint32_t* zpk = (uint32_t*)d_ws;   // 128 KB packed-fp16 z

    enc_kernel<<<NB / 8, 256, 0, stream>>>(x, We1, be1, We2, be2, We3, be3,
                                           We4, be4, zpk);
    dec_kernel<<<NU * 2, 256, 0, stream>>>(zpk, Wd1, bd1, Wd2, bd2,
                                           Wd3, bd3, Wd4, bd4, out);
}

// Round 11
// 52.301 us; speedup vs baseline: 2.9190x; 1.0758x over previous
//
#include <hip/hip_runtime.h>
#include <hip/hip_bf16.h>
#include <hip/hip_fp16.h>
#include <stdint.h>

#define NB 2048
#define NU 512
#define NL 32
#define NH 64

typedef float    f4    __attribute__((ext_vector_type(4)));
typedef uint32_t u32x4 __attribute__((ext_vector_type(4)));
typedef _Float16 h8    __attribute__((ext_vector_type(8)));
typedef _Float16 h2    __attribute__((ext_vector_type(2)));

__device__ __forceinline__ f4 mfma16h(u32x4 a, u32x4 b, f4 c) {
    return __builtin_amdgcn_mfma_f32_16x16x32_f16(
        __builtin_bit_cast(h8, a), __builtin_bit_cast(h8, b), c, 0, 0, 0);
}

// RNE fp16 pair pack (staging / encoder, one-time per value)
__device__ __forceinline__ uint32_t pk2h(float a, float b) {
    uint32_t la = (uint32_t)__half_as_ushort(__float2half_rn(a));
    uint32_t hb = (uint32_t)__half_as_ushort(__float2half_rn(b));
    return la | (hb << 16);
}

// RTZ fp16 pack (activations, 1 VALU op)
__device__ __forceinline__ uint32_t pk_rtz(float e, float o) {
    return __builtin_bit_cast(uint32_t, __builtin_amdgcn_cvt_pkrtz(e, o));
}

// pack + relu in 2 ops (identical to fmax-then-cvt)
__device__ __forceinline__ uint32_t pk_relu(float e, float o) {
    uint32_t r = pk_rtz(e, o);
    asm("v_pk_max_f16 %0, %1, 0" : "=v"(r) : "v"(r));
    return r;
}

// packed fp16 dot2 with f32 accumulate
__device__ __forceinline__ float dot2(uint32_t a, uint32_t b, float c) {
    return __builtin_amdgcn_fdot2(__builtin_bit_cast(h2, a),
                                  __builtin_bit_cast(h2, b), c, false);
}

// act exchange: 4x16-lane-group block transpose via permlane swaps
__device__ __forceinline__ void xch(uint32_t A, uint32_t B,
                                    uint32_t& o0, uint32_t& o1) {
    asm("v_permlane32_swap_b32 %0, %1" : "+v"(A), "+v"(B));
    asm("v_permlane16_swap_b32 %0, %1" : "+v"(A), "+v"(B));
    o0 = A; o1 = B;
}

// ---------------------------------------------------------------- encoder ---
// writes z pre-packed as fp16 pairs: zpk[row][c2] = pk2h(z[2c2], z[2c2+1])
__global__ __launch_bounds__(256)
void enc_kernel(const float* __restrict__ x,
                const float* __restrict__ We1, const float* __restrict__ be1,
                const float* __restrict__ We2, const float* __restrict__ be2,
                const float* __restrict__ We3, const float* __restrict__ be3,
                const float* __restrict__ We4, const float* __restrict__ be4,
                uint32_t* __restrict__ zpk)
{
    const int RE = 8;
    __shared__ float xs[RE][512];
    __shared__ float ws[128 * 64];
    __shared__ float h[RE][NH];
    __shared__ float h2s[RE][NH];

    const int t  = threadIdx.x;
    const int r0 = blockIdx.x * RE;

    {
        const f4* xv  = (const f4*)(x + (size_t)r0 * 512);
        f4*       xsv = (f4*)&xs[0][0];
        for (int i = t; i < RE * 512 / 4; i += 256) xsv[i] = xv[i];
    }

    const int j = t & 63;
    const int w = t >> 6;

    float acc0 = be1[j], acc1 = be1[j];
    for (int kc = 0; kc < 512; kc += 128) {
        __syncthreads();
        const f4* wv  = (const f4*)(We1 + (size_t)kc * 64);
        f4*       wsv = (f4*)ws;
        for (int i = t; i < 128 * 64 / 4; i += 256) wsv[i] = wv[i];
        __syncthreads();
        #pragma unroll 8
        for (int k = 0; k < 128; ++k) {
            float wval = ws[k * 64 + j];
            acc0 = fmaf(xs[w][kc + k],     wval, acc0);
            acc1 = fmaf(xs[w + 4][kc + k], wval, acc1);
        }
    }
    acc0 = fmaxf(acc0, 0.f); acc1 = fmaxf(acc1, 0.f);
    __syncthreads();
    h[w][j] = acc0; h[w + 4][j] = acc1;
    __syncthreads();

    acc0 = be2[j]; acc1 = be2[j];
    #pragma unroll
    for (int k = 0; k < 64; ++k) {
        float wval = We2[k * 64 + j];
        acc0 = fmaf(h[w][k],     wval, acc0);
        acc1 = fmaf(h[w + 4][k], wval, acc1);
    }
    acc0 = fmaxf(acc0, 0.f); acc1 = fmaxf(acc1, 0.f);
    h2s[w][j] = acc0; h2s[w + 4][j] = acc1;
    __syncthreads();

    acc0 = be3[j]; acc1 = be3[j];
    #pragma unroll
    for (int k = 0; k < 64; ++k) {
        float wval = We3[k * 64 + j];
        acc0 = fmaf(h2s[w][k],     wval, acc0);
        acc1 = fmaf(h2s[w + 4][k], wval, acc1);
    }
    acc0 = fmaxf(acc0, 0.f); acc1 = fmaxf(acc1, 0.f);
    h[w][j] = acc0; h[w + 4][j] = acc1;
    __syncthreads();

    const int j4  = t & 31;
    const int row = t >> 5;
    float acc = be4[j4];
    #pragma unroll
    for (int k = 0; k < 64; ++k)
        acc = fmaf(h[row][k], We4[k * 32 + j4], acc);
    float nb = __shfl_xor(acc, 1);
    if ((j4 & 1) == 0)
        zpk[(size_t)(r0 + row) * 16 + (j4 >> 1)] = pk2h(acc, nb);
}

// ---------------------------------------------------------------- decoder ---
// 512 blocks (1/unit), 4 waves; each wave runs TWO independent row-streams
// (rows it*128+rl and it*128+64+rl) stage-interleaved, 16 double-iters.
//
// Rationale (r9/r10 data): per-wave-iter wall tracks body size, invariant
// to wave count (2 vs 4 waves/SIMD: 47.5 vs 45.5 us) -> the limiter is the
// serial dependency chain inside each wave, not issue or TLP. Two
// independent streams give the scheduler ready work in every stall slot.
// LDS padded to 54.9 KB -> 2 blocks/CU target -> RA budget 256 (allocator
// law, r6-r9) for the ~140 VGPR + 80 AGPR demand.
template <int K2>
__device__ __forceinline__ void stageW(const float* __restrict__ g,
                                       uint32_t (*dst)[68], int t)
{
    for (int g4 = t; g4 < K2 * 16; g4 += 256) {
        const int k2 = g4 >> 4, c4 = (g4 & 15) << 2;
        f4 a = *(const f4*)(g + (size_t)(2 * k2) * NH + c4);
        f4 b = *(const f4*)(g + (size_t)(2 * k2 + 1) * NH + c4);
        u32x4 p;
        p[0] = pk2h(a[0], b[0]);
        p[1] = pk2h(a[1], b[1]);
        p[2] = pk2h(a[2], b[2]);
        p[3] = pk2h(a[3], b[3]);
        *(u32x4*)&dst[k2][c4] = p;
    }
}

__global__ __launch_bounds__(256)
void dec_kernel(const uint32_t* __restrict__ zpk,
                const float* __restrict__ Wd1, const float* __restrict__ bd1,
                const float* __restrict__ Wd2, const float* __restrict__ bd2,
                const float* __restrict__ Wd3, const float* __restrict__ bd3,
                const float* __restrict__ Wd4, const float* __restrict__ bd4,
                float* __restrict__ out)
{
    __shared__ uint32_t wpk1[16][68];    // fp16-pair packed W^T
    __shared__ uint32_t wpk2[32][68];
    __shared__ uint32_t wpk3[150][68];   // rows 32..149 = occupancy pad (see above)
    __shared__ float bsh[3][NH];
    __shared__ float w4s[NH];

    const int bid = blockIdx.x;
    // bijective unit swizzle: 16 consecutive u (one 64B out-line) share bid%8 -> one XCD
    const int u = ((bid & 7) << 4) | (((bid >> 3) & 3) << 7) | (bid >> 5);
    const int t = threadIdx.x;

    stageW<16>(Wd1 + (size_t)u * NL * NH, wpk1, t);
    stageW<32>(Wd2 + (size_t)u * NH * NH, wpk2, t);
    stageW<32>(Wd3 + (size_t)u * NH * NH, wpk3, t);
    if (t < NH) {
        bsh[0][t] = bd1[(size_t)u * NH + t];
        bsh[1][t] = bd2[(size_t)u * NH + t];
        bsh[2][t] = bd3[(size_t)u * NH + t];
        w4s[t]    = Wd4[(size_t)u * NH + t];
    }
    __syncthreads();

    const int w  = t >> 6;          // wave 0..3
    const int lr = t & 15;          // batch-row lane
    const int lg = (t & 63) >> 4;   // lane group 0..3
    const float b4 = bd4[u];

    // ---- register A-fragments (W^T), packed fp16 pairs from LDS ----
    u32x4 a1[4], a2[4][2], a3[4][2];
    #pragma unroll
    for (int mt = 0; mt < 4; ++mt) {
        const int c = lr + 16 * mt;
        #pragma unroll
        for (int i = 0; i < 4; ++i)
            a1[mt][i] = wpk1[lg * 4 + i][c];
        #pragma unroll
        for (int ks = 0; ks < 2; ++ks) {
            #pragma unroll
            for (int i = 0; i < 4; ++i) {
                a2[mt][ks][i] = wpk2[ks * 16 + lg * 4 + i][c];
                a3[mt][ks][i] = wpk3[ks * 16 + lg * 4 + i][c];
            }
        }
    }

    // ---- loop-invariant bias C-quads ----
    f4 bc1[4], bc2[4], bc3[4];
    #pragma unroll
    for (int mt = 0; mt < 4; ++mt) {
        bc1[mt] = *(const f4*)&bsh[0][16 * mt + lg * 4];
        bc2[mt] = *(const f4*)&bsh[1][16 * mt + lg * 4];
        bc3[mt] = *(const f4*)&bsh[2][16 * mt + lg * 4];
    }

    // packed wd4 (fp16 RNE)
    uint32_t wd4pk[4][2];
    #pragma unroll
    for (int mt = 0; mt < 4; ++mt) {
        const int c = 16 * mt + lg * 4;
        wd4pk[mt][0] = pk2h(w4s[c],     w4s[c + 1]);
        wd4pk[mt][1] = pk2h(w4s[c + 2], w4s[c + 3]);
    }

    const int rl = w * 16 + lr;     // block-local row of this lane (stream base)

    // two streams: rows it*128 + rl  and  it*128 + 64 + rl
    u32x4 zc[2];
    zc[0] = *(const u32x4*)(zpk + (size_t)rl * 16 + lg * 4);
    zc[1] = *(const u32x4*)(zpk + (size_t)(64 + rl) * 16 + lg * 4);

    for (int it = 0; it < 16; ++it) {
        const int rb    = it * 128 + rl;
        const int rbn   = ((it + 1) & 15) * 128 + rl;
        u32x4 zn[2];
        zn[0] = *(const u32x4*)(zpk + (size_t)rbn * 16 + lg * 4);
        zn[1] = *(const u32x4*)(zpk + (size_t)(rbn + 64) * 16 + lg * 4);

        f4 acc[2][4];
        uint32_t pk1_[2][4][2], pk2_[2][4][2];

        // ---- L1 (both streams) ----
        #pragma unroll
        for (int s = 0; s < 2; ++s)
            #pragma unroll
            for (int mt = 0; mt < 4; ++mt)
                acc[s][mt] = mfma16h(a1[mt], zc[s], bc1[mt]);

        #pragma unroll
        for (int s = 0; s < 2; ++s)
            #pragma unroll
            for (int mt = 0; mt < 4; ++mt) {
                pk1_[s][mt][0] = pk_relu(acc[s][mt][0], acc[s][mt][1]);
                pk1_[s][mt][1] = pk_relu(acc[s][mt][2], acc[s][mt][3]);
            }

        // ---- L2 ----
        #pragma unroll
        for (int s = 0; s < 2; ++s) {
            u32x4 bf;
            uint32_t b0, b2, b1, b3;
            xch(pk1_[s][0][0], pk1_[s][1][0], b0, b2);
            xch(pk1_[s][0][1], pk1_[s][1][1], b1, b3);
            bf[0] = b0; bf[1] = b1; bf[2] = b2; bf[3] = b3;
            #pragma unroll
            for (int mt = 0; mt < 4; ++mt)
                acc[s][mt] = mfma16h(a2[mt][0], bf, bc2[mt]);
        }
        #pragma unroll
        for (int s = 0; s < 2; ++s) {
            u32x4 bf;
            uint32_t b0, b2, b1, b3;
            xch(pk1_[s][2][0], pk1_[s][3][0], b0, b2);
            xch(pk1_[s][2][1], pk1_[s][3][1], b1, b3);
            bf[0] = b0; bf[1] = b1; bf[2] = b2; bf[3] = b3;
            #pragma unroll
            for (int mt = 0; mt < 4; ++mt)
                acc[s][mt] = mfma16h(a2[mt][1], bf, acc[s][mt]);
        }

        #pragma unroll
        for (int s = 0; s < 2; ++s)
            #pragma unroll
            for (int mt = 0; mt < 4; ++mt) {
                pk2_[s][mt][0] = pk_relu(acc[s][mt][0], acc[s][mt][1]);
                pk2_[s][mt][1] = pk_relu(acc[s][mt][2], acc[s][mt][3]);
            }

        // ---- L3 ----
        #pragma unroll
        for (int s = 0; s < 2; ++s) {
            u32x4 bf;
            uint32_t b0, b2, b1, b3;
            xch(pk2_[s][0][0], pk2_[s][1][0], b0, b2);
            xch(pk2_[s][0][1], pk2_[s][1][1], b1, b3);
            bf[0] = b0; bf[1] = b1; bf[2] = b2; bf[3] = b3;
            #pragma unroll
            for (int mt = 0; mt < 4; ++mt)
                acc[s][mt] = mfma16h(a3[mt][0], bf, bc3[mt]);
        }
        #pragma unroll
        for (int s = 0; s < 2; ++s) {
            u32x4 bf;
            uint32_t b0, b2, b1, b3;
            xch(pk2_[s][2][0], pk2_[s][3][0], b0, b2);
            xch(pk2_[s][2][1], pk2_[s][3][1], b1, b3);
            bf[0] = b0; bf[1] = b1; bf[2] = b2; bf[3] = b3;
            #pragma unroll
            for (int mt = 0; mt < 4; ++mt)
                acc[s][mt] = mfma16h(a3[mt][1], bf, acc[s][mt]);
        }

        // ---- L4 (both streams) ----
        float part[2] = {0.f, 0.f};
        #pragma unroll
        for (int s = 0; s < 2; ++s)
            #pragma unroll
            for (int mt = 0; mt < 4; ++mt) {
                uint32_t p0 = pk_relu(acc[s][mt][0], acc[s][mt][1]);
                uint32_t p1 = pk_relu(acc[s][mt][2], acc[s][mt][3]);
                part[s] = dot2(p0, wd4pk[mt][0], part[s]);
                part[s] = dot2(p1, wd4pk[mt][1], part[s]);
            }
        #pragma unroll
        for (int s = 0; s < 2; ++s) {
            part[s] += __shfl_xor(part[s], 16);
            part[s] += __shfl_xor(part[s], 32);
        }
        if ((t & 48) == 0) {
            out[(size_t)rb * NU + u]        = part[0] + b4;
            out[(size_t)(rb + 64) * NU + u] = part[1] + b4;
        }

        zc[0] = zn[0]; zc[1] = zn[1];
    }
}

// ----------------------------------------------------------------- launch ---
extern "C" void kernel_launch(void* const* d_in, const int* in_sizes, int n_in,
                              void* d_out, int out_size, void* d_ws, size_t ws_size,
                              hipStream_t stream)
{
    const float* x   = (const float*)d_in[0];
    const float* We1 = (const float*)d_in[1];
    const float* be1 = (const float*)d_in[2];
    const float* We2 = (const float*)d_in[3];
    const float* be2 = (const float*)d_in[4];
    const float* We3 = (const float*)d_in[5];
    const float* be3 = (const float*)d_in[6];
    const float* We4 = (const float*)d_in[7];
    const float* be4 = (const float*)d_in[8];
    const float* Wd1 = (const float*)d_in[9];
    const float* bd1 = (const float*)d_in[10];
    const float* Wd2 = (const float*)d_in[11];
    const float* bd2 = (const float*)d_in[12];
    const float* Wd3 = (const float*)d_in[13];
    const float* bd3 = (const float*)d_in[14];
    const float* Wd4 = (const float*)d_in[15];
    const float* bd4 = (const float*)d_in[16];
    float* out = (float*)d_out;

    uint32_t* zpk = (uint32_t*)d_ws;   // 128 KB packed-fp16 z

    enc_kernel<<<NB / 8, 256, 0, stream>>>(x, We1, be1, We2, be2, We3, be3,
                                           We4, be4, zpk);
    dec_kernel<<<NU, 256, 0, stream>>>(zpk, Wd1, bd1, Wd2, bd2,
                                       Wd3, bd3, Wd4, bd4, out);
}

// Round 12
// 48.304 us; speedup vs baseline: 3.1606x; 1.0827x over previous
//
#include <hip/hip_runtime.h>
#include <hip/hip_bf16.h>
#include <hip/hip_fp16.h>
#include <stdint.h>

#define NB 2048
#define NU 512
#define NL 32
#define NH 64

typedef float    f4    __attribute__((ext_vector_type(4)));
typedef uint32_t u32x4 __attribute__((ext_vector_type(4)));
typedef _Float16 h8    __attribute__((ext_vector_type(8)));
typedef _Float16 h2    __attribute__((ext_vector_type(2)));

__device__ __forceinline__ f4 mfma16h(u32x4 a, u32x4 b, f4 c) {
    return __builtin_amdgcn_mfma_f32_16x16x32_f16(
        __builtin_bit_cast(h8, a), __builtin_bit_cast(h8, b), c, 0, 0, 0);
}

// RNE fp16 pair pack (staging / encoder, one-time per value)
__device__ __forceinline__ uint32_t pk2h(float a, float b) {
    uint32_t la = (uint32_t)__half_as_ushort(__float2half_rn(a));
    uint32_t hb = (uint32_t)__half_as_ushort(__float2half_rn(b));
    return la | (hb << 16);
}

// RTZ fp16 pack (activations, 1 VALU op)
__device__ __forceinline__ uint32_t pk_rtz(float e, float o) {
    return __builtin_bit_cast(uint32_t, __builtin_amdgcn_cvt_pkrtz(e, o));
}

// pack + relu in 2 ops (identical to fmax-then-cvt); non-tied asm operands
__device__ __forceinline__ uint32_t pk_relu(float e, float o) {
    uint32_t r = pk_rtz(e, o);
    asm("v_pk_max_f16 %0, %1, 0" : "=v"(r) : "v"(r));
    return r;
}

// packed fp16 dot2 with f32 accumulate
__device__ __forceinline__ float dot2(uint32_t a, uint32_t b, float c) {
    return __builtin_amdgcn_fdot2(__builtin_bit_cast(h2, a),
                                  __builtin_bit_cast(h2, b), c, false);
}

// ---------------------------------------------------------------- encoder ---
// writes z pre-packed as fp16 pairs: zpk[row][c2] = pk2h(z[2c2], z[2c2+1])
__global__ __launch_bounds__(256)
void enc_kernel(const float* __restrict__ x,
                const float* __restrict__ We1, const float* __restrict__ be1,
                const float* __restrict__ We2, const float* __restrict__ be2,
                const float* __restrict__ We3, const float* __restrict__ be3,
                const float* __restrict__ We4, const float* __restrict__ be4,
                uint32_t* __restrict__ zpk)
{
    const int RE = 8;
    __shared__ float xs[RE][512];
    __shared__ float ws[128 * 64];
    __shared__ float h[RE][NH];
    __shared__ float h2s[RE][NH];

    const int t  = threadIdx.x;
    const int r0 = blockIdx.x * RE;

    {
        const f4* xv  = (const f4*)(x + (size_t)r0 * 512);
        f4*       xsv = (f4*)&xs[0][0];
        for (int i = t; i < RE * 512 / 4; i += 256) xsv[i] = xv[i];
    }

    const int j = t & 63;
    const int w = t >> 6;

    float acc0 = be1[j], acc1 = be1[j];
    for (int kc = 0; kc < 512; kc += 128) {
        __syncthreads();
        const f4* wv  = (const f4*)(We1 + (size_t)kc * 64);
        f4*       wsv = (f4*)ws;
        for (int i = t; i < 128 * 64 / 4; i += 256) wsv[i] = wv[i];
        __syncthreads();
        #pragma unroll 8
        for (int k = 0; k < 128; ++k) {
            float wval = ws[k * 64 + j];
            acc0 = fmaf(xs[w][kc + k],     wval, acc0);
            acc1 = fmaf(xs[w + 4][kc + k], wval, acc1);
        }
    }
    acc0 = fmaxf(acc0, 0.f); acc1 = fmaxf(acc1, 0.f);
    __syncthreads();
    h[w][j] = acc0; h[w + 4][j] = acc1;
    __syncthreads();

    acc0 = be2[j]; acc1 = be2[j];
    #pragma unroll
    for (int k = 0; k < 64; ++k) {
        float wval = We2[k * 64 + j];
        acc0 = fmaf(h[w][k],     wval, acc0);
        acc1 = fmaf(h[w + 4][k], wval, acc1);
    }
    acc0 = fmaxf(acc0, 0.f); acc1 = fmaxf(acc1, 0.f);
    h2s[w][j] = acc0; h2s[w + 4][j] = acc1;
    __syncthreads();

    acc0 = be3[j]; acc1 = be3[j];
    #pragma unroll
    for (int k = 0; k < 64; ++k) {
        float wval = We3[k * 64 + j];
        acc0 = fmaf(h2s[w][k],     wval, acc0);
        acc1 = fmaf(h2s[w + 4][k], wval, acc1);
    }
    acc0 = fmaxf(acc0, 0.f); acc1 = fmaxf(acc1, 0.f);
    h[w][j] = acc0; h[w + 4][j] = acc1;
    __syncthreads();

    const int j4  = t & 31;
    const int row = t >> 5;
    float acc = be4[j4];
    #pragma unroll
    for (int k = 0; k < 64; ++k)
        acc = fmaf(h[row][k], We4[k * 32 + j4], acc);
    float nb = __shfl_xor(acc, 1);
    if ((j4 & 1) == 0)
        zpk[(size_t)(r0 + row) * 16 + (j4 >> 1)] = pk2h(acc, nb);
}

// ---------------------------------------------------------------- decoder ---
// 512 blocks (1/unit), 4 waves x 2 row-streams x 16 rows, 16 double-iters.
//
// PERMUTED-FEATURE LAYOUT (this round's change): A-tile mt, tile-row j
// maps to out-feature f(mt,j) = (mt>>1)*32 + 8*(j>>2) + (mt&1)*4 + (j&3).
// With this assignment, each lane's MFMA-D quads are exactly the k-quads
// its OWN next-layer B-fragment needs: B words = the lane's pk_relu
// outputs, zero cross-lane exchange (r11's 16 permlane + tied-operand
// copies per stream-iter deleted; critical path = mfma -> 2 packs -> mfma).
// Same products, same order => bit-identical output to r9-r11.
// LDS padded to 54.9 KB -> 2 blocks/CU -> RA budget 256 (allocator law).
template <int K2>
__device__ __forceinline__ void stageW(const float* __restrict__ g,
                                       uint32_t (*dst)[68], int t)
{
    for (int g4 = t; g4 < K2 * 16; g4 += 256) {
        const int k2 = g4 >> 4, c4 = (g4 & 15) << 2;
        f4 a = *(const f4*)(g + (size_t)(2 * k2) * NH + c4);
        f4 b = *(const f4*)(g + (size_t)(2 * k2 + 1) * NH + c4);
        u32x4 p;
        p[0] = pk2h(a[0], b[0]);
        p[1] = pk2h(a[1], b[1]);
        p[2] = pk2h(a[2], b[2]);
        p[3] = pk2h(a[3], b[3]);
        *(u32x4*)&dst[k2][c4] = p;
    }
}

__global__ __launch_bounds__(256)
void dec_kernel(const uint32_t* __restrict__ zpk,
                const float* __restrict__ Wd1, const float* __restrict__ bd1,
                const float* __restrict__ Wd2, const float* __restrict__ bd2,
                const float* __restrict__ Wd3, const float* __restrict__ bd3,
                const float* __restrict__ Wd4, const float* __restrict__ bd4,
                float* __restrict__ out)
{
    __shared__ uint32_t wpk1[16][68];    // fp16-pair packed W^T
    __shared__ uint32_t wpk2[32][68];
    __shared__ uint32_t wpk3[150][68];   // rows 32..149 = occupancy pad
    __shared__ float bsh[3][NH];
    __shared__ float w4s[NH];

    const int bid = blockIdx.x;
    // bijective unit swizzle: 16 consecutive u (one 64B out-line) share bid%8 -> one XCD
    const int u = ((bid & 7) << 4) | (((bid >> 3) & 3) << 7) | (bid >> 5);
    const int t = threadIdx.x;

    stageW<16>(Wd1 + (size_t)u * NL * NH, wpk1, t);
    stageW<32>(Wd2 + (size_t)u * NH * NH, wpk2, t);
    stageW<32>(Wd3 + (size_t)u * NH * NH, wpk3, t);
    if (t < NH) {
        bsh[0][t] = bd1[(size_t)u * NH + t];
        bsh[1][t] = bd2[(size_t)u * NH + t];
        bsh[2][t] = bd3[(size_t)u * NH + t];
        w4s[t]    = Wd4[(size_t)u * NH + t];
    }
    __syncthreads();

    const int w  = t >> 6;          // wave 0..3
    const int lr = t & 15;          // batch-row lane
    const int lg = (t & 63) >> 4;   // lane group 0..3
    const float b4 = bd4[u];

    // permuted out-feature for (tile mt, tile-row lr)
    int cperm[4];
    #pragma unroll
    for (int mt = 0; mt < 4; ++mt)
        cperm[mt] = ((mt >> 1) << 5) + ((lr >> 2) << 3) + ((mt & 1) << 2) + (lr & 3);

    // ---- register A-fragments (W^T), permuted columns ----
    u32x4 a1[4], a2[4][2], a3[4][2];
    #pragma unroll
    for (int mt = 0; mt < 4; ++mt) {
        const int c = cperm[mt];
        #pragma unroll
        for (int i = 0; i < 4; ++i)
            a1[mt][i] = wpk1[lg * 4 + i][c];
        #pragma unroll
        for (int ks = 0; ks < 2; ++ks) {
            #pragma unroll
            for (int i = 0; i < 4; ++i) {
                a2[mt][ks][i] = wpk2[ks * 16 + lg * 4 + i][c];
                a3[mt][ks][i] = wpk3[ks * 16 + lg * 4 + i][c];
            }
        }
    }

    // lane's held feature-quad base for tile mt: bq = (mt>>1)*32 + 8*lg + (mt&1)*4
    int bq[4];
    #pragma unroll
    for (int mt = 0; mt < 4; ++mt)
        bq[mt] = ((mt >> 1) << 5) + (lg << 3) + ((mt & 1) << 2);

    // loop-invariant bias C-quads at permuted positions
    f4 bc1[4], bc2[4], bc3[4];
    #pragma unroll
    for (int mt = 0; mt < 4; ++mt) {
        bc1[mt] = *(const f4*)&bsh[0][bq[mt]];
        bc2[mt] = *(const f4*)&bsh[1][bq[mt]];
        bc3[mt] = *(const f4*)&bsh[2][bq[mt]];
    }

    // packed wd4 at permuted positions
    uint32_t wd4pk[4][2];
    #pragma unroll
    for (int mt = 0; mt < 4; ++mt) {
        wd4pk[mt][0] = pk2h(w4s[bq[mt]],     w4s[bq[mt] + 1]);
        wd4pk[mt][1] = pk2h(w4s[bq[mt] + 2], w4s[bq[mt] + 3]);
    }

    const int rl = w * 16 + lr;     // block-local row (stream base)

    u32x4 zc[2];
    zc[0] = *(const u32x4*)(zpk + (size_t)rl * 16 + lg * 4);
    zc[1] = *(const u32x4*)(zpk + (size_t)(64 + rl) * 16 + lg * 4);

    for (int it = 0; it < 16; ++it) {
        const int rb  = it * 128 + rl;
        const int rbn = ((it + 1) & 15) * 128 + rl;
        u32x4 zn[2];
        zn[0] = *(const u32x4*)(zpk + (size_t)rbn * 16 + lg * 4);
        zn[1] = *(const u32x4*)(zpk + (size_t)(rbn + 64) * 16 + lg * 4);

        f4 acc[2][4];

        // ---- L1 (both streams) ----
        #pragma unroll
        for (int s = 0; s < 2; ++s)
            #pragma unroll
            for (int mt = 0; mt < 4; ++mt)
                acc[s][mt] = mfma16h(a1[mt], zc[s], bc1[mt]);

        // ---- h1 B-frags: lane-local pack, no exchange ----
        u32x4 bf0[2], bf1[2];
        #pragma unroll
        for (int s = 0; s < 2; ++s) {
            bf0[s][0] = pk_relu(acc[s][0][0], acc[s][0][1]);
            bf0[s][1] = pk_relu(acc[s][0][2], acc[s][0][3]);
            bf0[s][2] = pk_relu(acc[s][1][0], acc[s][1][1]);
            bf0[s][3] = pk_relu(acc[s][1][2], acc[s][1][3]);
            bf1[s][0] = pk_relu(acc[s][2][0], acc[s][2][1]);
            bf1[s][1] = pk_relu(acc[s][2][2], acc[s][2][3]);
            bf1[s][2] = pk_relu(acc[s][3][0], acc[s][3][1]);
            bf1[s][3] = pk_relu(acc[s][3][2], acc[s][3][3]);
        }

        // ---- L2 ----
        #pragma unroll
        for (int s = 0; s < 2; ++s)
            #pragma unroll
            for (int mt = 0; mt < 4; ++mt)
                acc[s][mt] = mfma16h(a2[mt][0], bf0[s], bc2[mt]);
        #pragma unroll
        for (int s = 0; s < 2; ++s)
            #pragma unroll
            for (int mt = 0; mt < 4; ++mt)
                acc[s][mt] = mfma16h(a2[mt][1], bf1[s], acc[s][mt]);

        // ---- h2 B-frags ----
        #pragma unroll
        for (int s = 0; s < 2; ++s) {
            bf0[s][0] = pk_relu(acc[s][0][0], acc[s][0][1]);
            bf0[s][1] = pk_relu(acc[s][0][2], acc[s][0][3]);
            bf0[s][2] = pk_relu(acc[s][1][0], acc[s][1][1]);
            bf0[s][3] = pk_relu(acc[s][1][2], acc[s][1][3]);
            bf1[s][0] = pk_relu(acc[s][2][0], acc[s][2][1]);
            bf1[s][1] = pk_relu(acc[s][2][2], acc[s][2][3]);
            bf1[s][2] = pk_relu(acc[s][3][0], acc[s][3][1]);
            bf1[s][3] = pk_relu(acc[s][3][2], acc[s][3][3]);
        }

        // ---- L3 ----
        #pragma unroll
        for (int s = 0; s < 2; ++s)
            #pragma unroll
            for (int mt = 0; mt < 4; ++mt)
                acc[s][mt] = mfma16h(a3[mt][0], bf0[s], bc3[mt]);
        #pragma unroll
        for (int s = 0; s < 2; ++s)
            #pragma unroll
            for (int mt = 0; mt < 4; ++mt)
                acc[s][mt] = mfma16h(a3[mt][1], bf1[s], acc[s][mt]);

        // ---- L4: pack-relu h3 + dot2 (two chains per stream) ----
        #pragma unroll
        for (int s = 0; s < 2; ++s) {
            float pa = 0.f, pb = 0.f;
            #pragma unroll
            for (int mt = 0; mt < 4; ++mt) {
                uint32_t p0 = pk_relu(acc[s][mt][0], acc[s][mt][1]);
                uint32_t p1 = pk_relu(acc[s][mt][2], acc[s][mt][3]);
                pa = dot2(p0, wd4pk[mt][0], pa);
                pb = dot2(p1, wd4pk[mt][1], pb);
            }
            float part = pa + pb;
            part += __shfl_xor(part, 16);
            part += __shfl_xor(part, 32);
            if ((t & 48) == 0)
                out[(size_t)(rb + s * 64) * NU + u] = part + b4;
        }

        zc[0] = zn[0]; zc[1] = zn[1];
    }
}

// ----------------------------------------------------------------- launch ---
extern "C" void kernel_launch(void* const* d_in, const int* in_sizes, int n_in,
                              void* d_out, int out_size, void* d_ws, size_t ws_size,
                              hipStream_t stream)
{
    const float* x   = (const float*)d_in[0];
    const float* We1 = (const float*)d_in[1];
    const float* be1 = (const float*)d_in[2];
    const float* We2 = (const float*)d_in[3];
    const float* be2 = (const float*)d_in[4];
    const float* We3 = (const float*)d_in[5];
    const float* be3 = (const float*)d_in[6];
    const float* We4 = (const float*)d_in[7];
    const float* be4 = (const float*)d_in[8];
    const float* Wd1 = (const float*)d_in[9];
    const float* bd1 = (const float*)d_in[10];
    const float* Wd2 = (const float*)d_in[11];
    const float* bd2 = (const float*)d_in[12];
    const float* Wd3 = (const float*)d_in[13];
    const float* bd3 = (const float*)d_in[14];
    const float* Wd4 = (const float*)d_in[15];
    const float* bd4 = (const float*)d_in[16];
    float* out = (float*)d_out;

    uint32_t* zpk = (uint32_t*)d_ws;   // 128 KB packed-fp16 z

    enc_kernel<<<NB / 8, 256, 0, stream>>>(x, We1, be1, We2, be2, We3, be3,
                                           We4, be4, zpk);
    dec_kernel<<<NU, 256, 0, stream>>>(zpk, Wd1, bd1, Wd2, bd2,
                                       Wd3, bd3, Wd4, bd4, out);
}

// Round 13
// 47.646 us; speedup vs baseline: 3.2042x; 1.0138x over previous
//
#include <hip/hip_runtime.h>
#include <hip/hip_bf16.h>
#include <hip/hip_fp16.h>
#include <stdint.h>

#define NB 2048
#define NU 512
#define NL 32
#define NH 64

typedef float    f4    __attribute__((ext_vector_type(4)));
typedef uint32_t u32x4 __attribute__((ext_vector_type(4)));
typedef _Float16 h8    __attribute__((ext_vector_type(8)));
typedef _Float16 h2    __attribute__((ext_vector_type(2)));

__device__ __forceinline__ f4 mfma16h(u32x4 a, u32x4 b, f4 c) {
    return __builtin_amdgcn_mfma_f32_16x16x32_f16(
        __builtin_bit_cast(h8, a), __builtin_bit_cast(h8, b), c, 0, 0, 0);
}

// RNE fp16 pair pack (staging / encoder, one-time per value)
__device__ __forceinline__ uint32_t pk2h(float a, float b) {
    uint32_t la = (uint32_t)__half_as_ushort(__float2half_rn(a));
    uint32_t hb = (uint32_t)__half_as_ushort(__float2half_rn(b));
    return la | (hb << 16);
}

// RTZ fp16 pack (activations, 1 VALU op)
__device__ __forceinline__ uint32_t pk_rtz(float e, float o) {
    return __builtin_bit_cast(uint32_t, __builtin_amdgcn_cvt_pkrtz(e, o));
}

// pack + relu in 2 ops (identical to fmax-then-cvt)
__device__ __forceinline__ uint32_t pk_relu(float e, float o) {
    uint32_t r = pk_rtz(e, o);
    asm("v_pk_max_f16 %0, %1, 0" : "=v"(r) : "v"(r));
    return r;
}

// packed fp16 dot2 with f32 accumulate
__device__ __forceinline__ float dot2(uint32_t a, uint32_t b, float c) {
    return __builtin_amdgcn_fdot2(__builtin_bit_cast(h2, a),
                                  __builtin_bit_cast(h2, b), c, false);
}

// ---------------------------------------------------------------- encoder ---
// 256 blocks x 512 threads (8 waves -> 2 waves/SIMD, was 1), 8 rows/block,
// one row per wave for L1-L3. Same per-row fma chain order as before ->
// bit-identical z.
__global__ __launch_bounds__(512)
void enc_kernel(const float* __restrict__ x,
                const float* __restrict__ We1, const float* __restrict__ be1,
                const float* __restrict__ We2, const float* __restrict__ be2,
                const float* __restrict__ We3, const float* __restrict__ be3,
                const float* __restrict__ We4, const float* __restrict__ be4,
                uint32_t* __restrict__ zpk)
{
    const int RE = 8;
    __shared__ float xs[RE][512];
    __shared__ float ws[128 * 64];
    __shared__ float h[RE][NH];
    __shared__ float h2s[RE][NH];

    const int t  = threadIdx.x;
    const int r0 = blockIdx.x * RE;

    {
        const f4* xv  = (const f4*)(x + (size_t)r0 * 512);
        f4*       xsv = (f4*)&xs[0][0];
        for (int i = t; i < RE * 512 / 4; i += 512) xsv[i] = xv[i];
    }

    const int j = t & 63;
    const int w = t >> 6;          // wave 0..7 = row

    float acc0 = be1[j];
    for (int kc = 0; kc < 512; kc += 128) {
        __syncthreads();
        const f4* wv  = (const f4*)(We1 + (size_t)kc * 64);
        f4*       wsv = (f4*)ws;
        for (int i = t; i < 128 * 64 / 4; i += 512) wsv[i] = wv[i];
        __syncthreads();
        #pragma unroll 8
        for (int k = 0; k < 128; ++k)
            acc0 = fmaf(xs[w][kc + k], ws[k * 64 + j], acc0);
    }
    acc0 = fmaxf(acc0, 0.f);
    __syncthreads();
    h[w][j] = acc0;
    __syncthreads();

    acc0 = be2[j];
    #pragma unroll
    for (int k = 0; k < 64; ++k)
        acc0 = fmaf(h[w][k], We2[k * 64 + j], acc0);
    acc0 = fmaxf(acc0, 0.f);
    h2s[w][j] = acc0;
    __syncthreads();

    acc0 = be3[j];
    #pragma unroll
    for (int k = 0; k < 64; ++k)
        acc0 = fmaf(h2s[w][k], We3[k * 64 + j], acc0);
    acc0 = fmaxf(acc0, 0.f);
    h[w][j] = acc0;
    __syncthreads();

    if (t < 256) {
        const int j4  = t & 31;
        const int row = t >> 5;    // 0..7
        float acc = be4[j4];
        #pragma unroll
        for (int k = 0; k < 64; ++k)
            acc = fmaf(h[row][k], We4[k * 32 + j4], acc);
        float nb = __shfl_xor(acc, 1);
        if ((j4 & 1) == 0)
            zpk[(size_t)(r0 + row) * 16 + (j4 >> 1)] = pk2h(acc, nb);
    }
}

// ---------------------------------------------------------------- decoder ---
// 1024 blocks = 2/unit (batch halves), 4 waves x 2 row-streams, 8 double-iters.
// Exchange-free permuted-feature body (r12) at 4 waves/SIMD: LDS padded to
// 33.7 KB -> 4 blocks/CU -> RA budget 128 >= ~104 demand (allocator law).
// r10's "TLP null" was measured on the long-chain permlane body; this body's
// chain is mfma -> 2 packs -> mfma, so wave count should now fill the slots.
template <int K2>
__device__ __forceinline__ void stageW(const float* __restrict__ g,
                                       uint32_t (*dst)[68], int t)
{
    for (int g4 = t; g4 < K2 * 16; g4 += 256) {
        const int k2 = g4 >> 4, c4 = (g4 & 15) << 2;
        f4 a = *(const f4*)(g + (size_t)(2 * k2) * NH + c4);
        f4 b = *(const f4*)(g + (size_t)(2 * k2 + 1) * NH + c4);
        u32x4 p;
        p[0] = pk2h(a[0], b[0]);
        p[1] = pk2h(a[1], b[1]);
        p[2] = pk2h(a[2], b[2]);
        p[3] = pk2h(a[3], b[3]);
        *(u32x4*)&dst[k2][c4] = p;
    }
}

__global__ __launch_bounds__(256)
void dec_kernel(const uint32_t* __restrict__ zpk,
                const float* __restrict__ Wd1, const float* __restrict__ bd1,
                const float* __restrict__ Wd2, const float* __restrict__ bd2,
                const float* __restrict__ Wd3, const float* __restrict__ bd3,
                const float* __restrict__ Wd4, const float* __restrict__ bd4,
                float* __restrict__ out)
{
    __shared__ uint32_t wpk1[16][68];   // fp16-pair packed W^T
    __shared__ uint32_t wpk2[32][68];
    __shared__ uint32_t wpk3[72][68];   // rows 32..71 = occupancy pad -> 33.7 KB
    __shared__ float bsh[3][NH];
    __shared__ float w4s[NH];

    const int bid  = blockIdx.x;
    const int half = bid >> 9;          // batch half
    const int ub   = bid & 511;
    // bijective unit swizzle: 16 consecutive u (one 64B out-line) share bid%8 -> one XCD
    const int u = ((ub & 7) << 4) | (((ub >> 3) & 3) << 7) | (ub >> 5);
    const int t = threadIdx.x;

    stageW<16>(Wd1 + (size_t)u * NL * NH, wpk1, t);
    stageW<32>(Wd2 + (size_t)u * NH * NH, wpk2, t);
    stageW<32>(Wd3 + (size_t)u * NH * NH, wpk3, t);
    if (t < NH) {
        bsh[0][t] = bd1[(size_t)u * NH + t];
        bsh[1][t] = bd2[(size_t)u * NH + t];
        bsh[2][t] = bd3[(size_t)u * NH + t];
        w4s[t]    = Wd4[(size_t)u * NH + t];
    }
    __syncthreads();

    const int w  = t >> 6;          // wave 0..3
    const int lr = t & 15;          // batch-row lane
    const int lg = (t & 63) >> 4;   // lane group 0..3
    const float b4 = bd4[u];

    // permuted out-feature for (tile mt, tile-row lr)
    int cperm[4];
    #pragma unroll
    for (int mt = 0; mt < 4; ++mt)
        cperm[mt] = ((mt >> 1) << 5) + ((lr >> 2) << 3) + ((mt & 1) << 2) + (lr & 3);

    // ---- register A-fragments (W^T), permuted columns ----
    u32x4 a1[4], a2[4][2], a3[4][2];
    #pragma unroll
    for (int mt = 0; mt < 4; ++mt) {
        const int c = cperm[mt];
        #pragma unroll
        for (int i = 0; i < 4; ++i)
            a1[mt][i] = wpk1[lg * 4 + i][c];
        #pragma unroll
        for (int ks = 0; ks < 2; ++ks) {
            #pragma unroll
            for (int i = 0; i < 4; ++i) {
                a2[mt][ks][i] = wpk2[ks * 16 + lg * 4 + i][c];
                a3[mt][ks][i] = wpk3[ks * 16 + lg * 4 + i][c];
            }
        }
    }

    // lane's held feature-quad base for tile mt
    int bq[4];
    #pragma unroll
    for (int mt = 0; mt < 4; ++mt)
        bq[mt] = ((mt >> 1) << 5) + (lg << 3) + ((mt & 1) << 2);

    f4 bc1[4], bc2[4], bc3[4];
    #pragma unroll
    for (int mt = 0; mt < 4; ++mt) {
        bc1[mt] = *(const f4*)&bsh[0][bq[mt]];
        bc2[mt] = *(const f4*)&bsh[1][bq[mt]];
        bc3[mt] = *(const f4*)&bsh[2][bq[mt]];
    }

    uint32_t wd4pk[4][2];
    #pragma unroll
    for (int mt = 0; mt < 4; ++mt) {
        wd4pk[mt][0] = pk2h(w4s[bq[mt]],     w4s[bq[mt] + 1]);
        wd4pk[mt][1] = pk2h(w4s[bq[mt] + 2], w4s[bq[mt] + 3]);
    }

    const int rl  = w * 16 + lr;        // block-local row (stream base)
    const int it0 = half * 8;

    u32x4 zc[2];
    zc[0] = *(const u32x4*)(zpk + (size_t)(it0 * 128 + rl) * 16 + lg * 4);
    zc[1] = *(const u32x4*)(zpk + (size_t)(it0 * 128 + 64 + rl) * 16 + lg * 4);

    for (int it = it0; it < it0 + 8; ++it) {
        const int rb  = it * 128 + rl;
        const int rbn = (it0 + ((it - it0 + 1) & 7)) * 128 + rl;
        u32x4 zn[2];
        zn[0] = *(const u32x4*)(zpk + (size_t)rbn * 16 + lg * 4);
        zn[1] = *(const u32x4*)(zpk + (size_t)(rbn + 64) * 16 + lg * 4);

        f4 acc[2][4];

        // ---- L1 (both streams) ----
        #pragma unroll
        for (int s = 0; s < 2; ++s)
            #pragma unroll
            for (int mt = 0; mt < 4; ++mt)
                acc[s][mt] = mfma16h(a1[mt], zc[s], bc1[mt]);

        // ---- h1 B-frags: lane-local pack, no exchange ----
        u32x4 bf0[2], bf1[2];
        #pragma unroll
        for (int s = 0; s < 2; ++s) {
            bf0[s][0] = pk_relu(acc[s][0][0], acc[s][0][1]);
            bf0[s][1] = pk_relu(acc[s][0][2], acc[s][0][3]);
            bf0[s][2] = pk_relu(acc[s][1][0], acc[s][1][1]);
            bf0[s][3] = pk_relu(acc[s][1][2], acc[s][1][3]);
            bf1[s][0] = pk_relu(acc[s][2][0], acc[s][2][1]);
            bf1[s][1] = pk_relu(acc[s][2][2], acc[s][2][3]);
            bf1[s][2] = pk_relu(acc[s][3][0], acc[s][3][1]);
            bf1[s][3] = pk_relu(acc[s][3][2], acc[s][3][3]);
        }

        // ---- L2 ----
        #pragma unroll
        for (int s = 0; s < 2; ++s)
            #pragma unroll
            for (int mt = 0; mt < 4; ++mt)
                acc[s][mt] = mfma16h(a2[mt][0], bf0[s], bc2[mt]);
        #pragma unroll
        for (int s = 0; s < 2; ++s)
            #pragma unroll
            for (int mt = 0; mt < 4; ++mt)
                acc[s][mt] = mfma16h(a2[mt][1], bf1[s], acc[s][mt]);

        // ---- h2 B-frags ----
        #pragma unroll
        for (int s = 0; s < 2; ++s) {
            bf0[s][0] = pk_relu(acc[s][0][0], acc[s][0][1]);
            bf0[s][1] = pk_relu(acc[s][0][2], acc[s][0][3]);
            bf0[s][2] = pk_relu(acc[s][1][0], acc[s][1][1]);
            bf0[s][3] = pk_relu(acc[s][1][2], acc[s][1][3]);
            bf1[s][0] = pk_relu(acc[s][2][0], acc[s][2][1]);
            bf1[s][1] = pk_relu(acc[s][2][2], acc[s][2][3]);
            bf1[s][2] = pk_relu(acc[s][3][0], acc[s][3][1]);
            bf1[s][3] = pk_relu(acc[s][3][2], acc[s][3][3]);
        }

        // ---- L3 ----
        #pragma unroll
        for (int s = 0; s < 2; ++s)
            #pragma unroll
            for (int mt = 0; mt < 4; ++mt)
                acc[s][mt] = mfma16h(a3[mt][0], bf0[s], bc3[mt]);
        #pragma unroll
        for (int s = 0; s < 2; ++s)
            #pragma unroll
            for (int mt = 0; mt < 4; ++mt)
                acc[s][mt] = mfma16h(a3[mt][1], bf1[s], acc[s][mt]);

        // ---- L4: pack-relu h3 + dot2 ----
        #pragma unroll
        for (int s = 0; s < 2; ++s) {
            float pa = 0.f, pb = 0.f;
            #pragma unroll
            for (int mt = 0; mt < 4; ++mt) {
                uint32_t p0 = pk_relu(acc[s][mt][0], acc[s][mt][1]);
                uint32_t p1 = pk_relu(acc[s][mt][2], acc[s][mt][3]);
                pa = dot2(p0, wd4pk[mt][0], pa);
                pb = dot2(p1, wd4pk[mt][1], pb);
            }
            float part = pa + pb;
            part += __shfl_xor(part, 16);
            part += __shfl_xor(part, 32);
            if ((t & 48) == 0)
                out[(size_t)(rb + s * 64) * NU + u] = part + b4;
        }

        zc[0] = zn[0]; zc[1] = zn[1];
    }
}

// ----------------------------------------------------------------- launch ---
extern "C" void kernel_launch(void* const* d_in, const int* in_sizes, int n_in,
                              void* d_out, int out_size, void* d_ws, size_t ws_size,
                              hipStream_t stream)
{
    const float* x   = (const float*)d_in[0];
    const float* We1 = (const float*)d_in[1];
    const float* be1 = (const float*)d_in[2];
    const float* We2 = (const float*)d_in[3];
    const float* be2 = (const float*)d_in[4];
    const float* We3 = (const float*)d_in[5];
    const float* be3 = (const float*)d_in[6];
    const float* We4 = (const float*)d_in[7];
    const float* be4 = (const float*)d_in[8];
    const float* Wd1 = (const float*)d_in[9];
    const float* bd1 = (const float*)d_in[10];
    const float* Wd2 = (const float*)d_in[11];
    const float* bd2 = (const float*)d_in[12];
    const float* Wd3 = (const float*)d_in[13];
    const float* bd3 = (const float*)d_in[14];
    const float* Wd4 = (const float*)d_in[15];
    const float* bd4 = (const float*)d_in[16];
    float* out = (float*)d_out;

    uint32_t* zpk = (uint32_t*)d_ws;   // 128 KB packed-fp16 z

    enc_kernel<<<NB / 8, 512, 0, stream>>>(x, We1, be1, We2, be2, We3, be3,
                                           We4, be4, zpk);
    dec_kernel<<<NU * 2, 256, 0, stream>>>(zpk, Wd1, bd1, Wd2, bd2,
                                           Wd3, bd3, Wd4, bd4, out);
}

// Round 14
// 44.858 us; speedup vs baseline: 3.4034x; 1.0622x over previous
//
#include <hip/hip_runtime.h>
#include <hip/hip_bf16.h>
#include <hip/hip_fp16.h>
#include <stdint.h>

#define NB 2048
#define NU 512
#define NL 32
#define NH 64

typedef float    f4    __attribute__((ext_vector_type(4)));
typedef uint32_t u32x4 __attribute__((ext_vector_type(4)));
typedef _Float16 h8    __attribute__((ext_vector_type(8)));
typedef _Float16 h2    __attribute__((ext_vector_type(2)));

__device__ __forceinline__ f4 mfma16h(u32x4 a, u32x4 b, f4 c) {
    return __builtin_amdgcn_mfma_f32_16x16x32_f16(
        __builtin_bit_cast(h8, a), __builtin_bit_cast(h8, b), c, 0, 0, 0);
}

// RNE fp16 pair pack (staging / encoder, one-time per value)
__device__ __forceinline__ uint32_t pk2h(float a, float b) {
    uint32_t la = (uint32_t)__half_as_ushort(__float2half_rn(a));
    uint32_t hb = (uint32_t)__half_as_ushort(__float2half_rn(b));
    return la | (hb << 16);
}

// RTZ fp16 pack (activations, 1 VALU op)
__device__ __forceinline__ uint32_t pk_rtz(float e, float o) {
    return __builtin_bit_cast(uint32_t, __builtin_amdgcn_cvt_pkrtz(e, o));
}

// pack + relu in 2 ops (identical to fmax-then-cvt)
__device__ __forceinline__ uint32_t pk_relu(float e, float o) {
    uint32_t r = pk_rtz(e, o);
    asm("v_pk_max_f16 %0, %1, 0" : "=v"(r) : "v"(r));
    return r;
}

// packed fp16 dot2 with f32 accumulate
__device__ __forceinline__ float dot2(uint32_t a, uint32_t b, float c) {
    return __builtin_amdgcn_fdot2(__builtin_bit_cast(h2, a),
                                  __builtin_bit_cast(h2, b), c, false);
}

// butterfly sum over lane-bits 4 and 5 via permlane swaps (VALU only, no DS).
// swap16(a,b): a[16:31]<->b[0:15], a[48:63]<->b[32:47]; with b=copy(x),
// a+b = x + x^16 per lane. Then same with permlane32 for ^32.
// Same add association as shfl_xor version -> bit-identical.
__device__ __forceinline__ float red_lg(float x) {
    float a = x, b = x;
    asm("v_permlane16_swap_b32 %0, %1" : "+v"(a), "+v"(b));
    x = a + b;
    a = x; b = x;
    asm("v_permlane32_swap_b32 %0, %1" : "+v"(a), "+v"(b));
    return a + b;
}

// ---------------------------------------------------------------- encoder ---
// 256 blocks x 512 threads (2 waves/SIMD), 8 rows/block, 1 row/wave L1-L3.
__global__ __launch_bounds__(512)
void enc_kernel(const float* __restrict__ x,
                const float* __restrict__ We1, const float* __restrict__ be1,
                const float* __restrict__ We2, const float* __restrict__ be2,
                const float* __restrict__ We3, const float* __restrict__ be3,
                const float* __restrict__ We4, const float* __restrict__ be4,
                uint32_t* __restrict__ zpk)
{
    const int RE = 8;
    __shared__ float xs[RE][512];
    __shared__ float ws[128 * 64];
    __shared__ float h[RE][NH];
    __shared__ float h2s[RE][NH];

    const int t  = threadIdx.x;
    const int r0 = blockIdx.x * RE;

    {
        const f4* xv  = (const f4*)(x + (size_t)r0 * 512);
        f4*       xsv = (f4*)&xs[0][0];
        for (int i = t; i < RE * 512 / 4; i += 512) xsv[i] = xv[i];
    }

    const int j = t & 63;
    const int w = t >> 6;          // wave 0..7 = row

    float acc0 = be1[j];
    for (int kc = 0; kc < 512; kc += 128) {
        __syncthreads();
        const f4* wv  = (const f4*)(We1 + (size_t)kc * 64);
        f4*       wsv = (f4*)ws;
        for (int i = t; i < 128 * 64 / 4; i += 512) wsv[i] = wv[i];
        __syncthreads();
        #pragma unroll 8
        for (int k = 0; k < 128; ++k)
            acc0 = fmaf(xs[w][kc + k], ws[k * 64 + j], acc0);
    }
    acc0 = fmaxf(acc0, 0.f);
    __syncthreads();
    h[w][j] = acc0;
    __syncthreads();

    acc0 = be2[j];
    #pragma unroll
    for (int k = 0; k < 64; ++k)
        acc0 = fmaf(h[w][k], We2[k * 64 + j], acc0);
    acc0 = fmaxf(acc0, 0.f);
    h2s[w][j] = acc0;
    __syncthreads();

    acc0 = be3[j];
    #pragma unroll
    for (int k = 0; k < 64; ++k)
        acc0 = fmaf(h2s[w][k], We3[k * 64 + j], acc0);
    acc0 = fmaxf(acc0, 0.f);
    h[w][j] = acc0;
    __syncthreads();

    if (t < 256) {
        const int j4  = t & 31;
        const int row = t >> 5;    // 0..7
        float acc = be4[j4];
        #pragma unroll
        for (int k = 0; k < 64; ++k)
            acc = fmaf(h[row][k], We4[k * 32 + j4], acc);
        float nb = __shfl_xor(acc, 1);
        if ((j4 & 1) == 0)
            zpk[(size_t)(r0 + row) * 16 + (j4 >> 1)] = pk2h(acc, nb);
    }
}

// ---------------------------------------------------------------- decoder ---
// 512 blocks (1/unit), 4 waves x FOUR row-streams x 16 rows, 8 macro-iters.
// r13 adjudicated the 2x2: TLP null at any wave count; per-double-iter cost
// ~3000 cyc vs ~450 static issue -> per-wave stage-latency with no filler.
// This round: 4 independent chains per wave (deep ILP) + permlane reduce
// (removes the 2x ~120cy DS-shfl tail) + biases via LDS broadcast reads
// (frees 48 regs). LDS padded to 54.9 KB -> 2 blocks/CU -> RA budget 256
// (allocator law) for the ~236-reg peak.
template <int K2>
__device__ __forceinline__ void stageW(const float* __restrict__ g,
                                       uint32_t (*dst)[68], int t)
{
    for (int g4 = t; g4 < K2 * 16; g4 += 256) {
        const int k2 = g4 >> 4, c4 = (g4 & 15) << 2;
        f4 a = *(const f4*)(g + (size_t)(2 * k2) * NH + c4);
        f4 b = *(const f4*)(g + (size_t)(2 * k2 + 1) * NH + c4);
        u32x4 p;
        p[0] = pk2h(a[0], b[0]);
        p[1] = pk2h(a[1], b[1]);
        p[2] = pk2h(a[2], b[2]);
        p[3] = pk2h(a[3], b[3]);
        *(u32x4*)&dst[k2][c4] = p;
    }
}

__global__ __launch_bounds__(256)
void dec_kernel(const uint32_t* __restrict__ zpk,
                const float* __restrict__ Wd1, const float* __restrict__ bd1,
                const float* __restrict__ Wd2, const float* __restrict__ bd2,
                const float* __restrict__ Wd3, const float* __restrict__ bd3,
                const float* __restrict__ Wd4, const float* __restrict__ bd4,
                float* __restrict__ out)
{
    __shared__ uint32_t wpk1[16][68];    // fp16-pair packed W^T
    __shared__ uint32_t wpk2[32][68];
    __shared__ uint32_t wpk3[150][68];   // rows 32..149 = occupancy pad
    __shared__ float bsh[3][NH];
    __shared__ float w4s[NH];

    const int bid = blockIdx.x;
    // bijective unit swizzle: 16 consecutive u (one 64B out-line) share bid%8 -> one XCD
    const int u = ((bid & 7) << 4) | (((bid >> 3) & 3) << 7) | (bid >> 5);
    const int t = threadIdx.x;

    stageW<16>(Wd1 + (size_t)u * NL * NH, wpk1, t);
    stageW<32>(Wd2 + (size_t)u * NH * NH, wpk2, t);
    stageW<32>(Wd3 + (size_t)u * NH * NH, wpk3, t);
    if (t < NH) {
        bsh[0][t] = bd1[(size_t)u * NH + t];
        bsh[1][t] = bd2[(size_t)u * NH + t];
        bsh[2][t] = bd3[(size_t)u * NH + t];
        w4s[t]    = Wd4[(size_t)u * NH + t];
    }
    __syncthreads();

    const int w  = t >> 6;          // wave 0..3
    const int lr = t & 15;          // batch-row lane
    const int lg = (t & 63) >> 4;   // lane group 0..3
    const float b4 = bd4[u];

    // permuted out-feature for (tile mt, tile-row lr)
    int cperm[4];
    #pragma unroll
    for (int mt = 0; mt < 4; ++mt)
        cperm[mt] = ((mt >> 1) << 5) + ((lr >> 2) << 3) + ((mt & 1) << 2) + (lr & 3);

    // ---- register A-fragments (W^T), permuted columns ----
    u32x4 a1[4], a2[4][2], a3[4][2];
    #pragma unroll
    for (int mt = 0; mt < 4; ++mt) {
        const int c = cperm[mt];
        #pragma unroll
        for (int i = 0; i < 4; ++i)
            a1[mt][i] = wpk1[lg * 4 + i][c];
        #pragma unroll
        for (int ks = 0; ks < 2; ++ks) {
            #pragma unroll
            for (int i = 0; i < 4; ++i) {
                a2[mt][ks][i] = wpk2[ks * 16 + lg * 4 + i][c];
                a3[mt][ks][i] = wpk3[ks * 16 + lg * 4 + i][c];
            }
        }
    }

    // lane's held feature-quad base for tile mt
    int bq[4];
    #pragma unroll
    for (int mt = 0; mt < 4; ++mt)
        bq[mt] = ((mt >> 1) << 5) + (lg << 3) + ((mt & 1) << 2);

    // packed wd4 (8 resident regs)
    uint32_t wd4pk[4][2];
    #pragma unroll
    for (int mt = 0; mt < 4; ++mt) {
        wd4pk[mt][0] = pk2h(w4s[bq[mt]],     w4s[bq[mt] + 1]);
        wd4pk[mt][1] = pk2h(w4s[bq[mt] + 2], w4s[bq[mt] + 3]);
    }

    const int rl = w * 16 + lr;     // block-local row (stream base)

    u32x4 zc[4];
    #pragma unroll
    for (int s = 0; s < 4; ++s)
        zc[s] = *(const u32x4*)(zpk + (size_t)(rl + s * 64) * 16 + lg * 4);

    for (int it = 0; it < 8; ++it) {
        const int rb  = it * 256 + rl;
        const int rbn = ((it + 1) & 7) * 256 + rl;

        f4 acc[4][4];

        // ---- L1 (all 4 streams; bias via LDS broadcast) ----
        {
            f4 c0 = *(const f4*)&bsh[0][bq[0]];
            f4 c1 = *(const f4*)&bsh[0][bq[1]];
            f4 c2 = *(const f4*)&bsh[0][bq[2]];
            f4 c3 = *(const f4*)&bsh[0][bq[3]];
            #pragma unroll
            for (int s = 0; s < 4; ++s) {
                acc[s][0] = mfma16h(a1[0], zc[s], c0);
                acc[s][1] = mfma16h(a1[1], zc[s], c1);
                acc[s][2] = mfma16h(a1[2], zc[s], c2);
                acc[s][3] = mfma16h(a1[3], zc[s], c3);
            }
        }

        // prefetch next iter's z (zc consumed above)
        u32x4 zn[4];
        #pragma unroll
        for (int s = 0; s < 4; ++s)
            zn[s] = *(const u32x4*)(zpk + (size_t)(rbn + s * 64) * 16 + lg * 4);

        // ---- L2 + L3 per stream (bf liveness local; streams independent) ----
        f4 bc2[4], bc3[4];
        #pragma unroll
        for (int mt = 0; mt < 4; ++mt) {
            bc2[mt] = *(const f4*)&bsh[1][bq[mt]];
            bc3[mt] = *(const f4*)&bsh[2][bq[mt]];
        }
        #pragma unroll
        for (int s = 0; s < 4; ++s) {
            u32x4 bf0, bf1;
            bf0[0] = pk_relu(acc[s][0][0], acc[s][0][1]);
            bf0[1] = pk_relu(acc[s][0][2], acc[s][0][3]);
            bf0[2] = pk_relu(acc[s][1][0], acc[s][1][1]);
            bf0[3] = pk_relu(acc[s][1][2], acc[s][1][3]);
            bf1[0] = pk_relu(acc[s][2][0], acc[s][2][1]);
            bf1[1] = pk_relu(acc[s][2][2], acc[s][2][3]);
            bf1[2] = pk_relu(acc[s][3][0], acc[s][3][1]);
            bf1[3] = pk_relu(acc[s][3][2], acc[s][3][3]);

            #pragma unroll
            for (int mt = 0; mt < 4; ++mt)
                acc[s][mt] = mfma16h(a2[mt][0], bf0, bc2[mt]);
            #pragma unroll
            for (int mt = 0; mt < 4; ++mt)
                acc[s][mt] = mfma16h(a2[mt][1], bf1, acc[s][mt]);

            bf0[0] = pk_relu(acc[s][0][0], acc[s][0][1]);
            bf0[1] = pk_relu(acc[s][0][2], acc[s][0][3]);
            bf0[2] = pk_relu(acc[s][1][0], acc[s][1][1]);
            bf0[3] = pk_relu(acc[s][1][2], acc[s][1][3]);
            bf1[0] = pk_relu(acc[s][2][0], acc[s][2][1]);
            bf1[1] = pk_relu(acc[s][2][2], acc[s][2][3]);
            bf1[2] = pk_relu(acc[s][3][0], acc[s][3][1]);
            bf1[3] = pk_relu(acc[s][3][2], acc[s][3][3]);

            #pragma unroll
            for (int mt = 0; mt < 4; ++mt)
                acc[s][mt] = mfma16h(a3[mt][0], bf0, bc3[mt]);
            #pragma unroll
            for (int mt = 0; mt < 4; ++mt)
                acc[s][mt] = mfma16h(a3[mt][1], bf1, acc[s][mt]);
        }

        // ---- L4: pack-relu h3 + dot2 + permlane reduce (no DS) ----
        #pragma unroll
        for (int s = 0; s < 4; ++s) {
            float pa = 0.f, pb = 0.f;
            #pragma unroll
            for (int mt = 0; mt < 4; ++mt) {
                uint32_t p0 = pk_relu(acc[s][mt][0], acc[s][mt][1]);
                uint32_t p1 = pk_relu(acc[s][mt][2], acc[s][mt][3]);
                pa = dot2(p0, wd4pk[mt][0], pa);
                pb = dot2(p1, wd4pk[mt][1], pb);
            }
            float part = red_lg(pa + pb);
            if ((t & 48) == 0)
                out[(size_t)(rb + s * 64) * NU + u] = part + b4;
        }

        #pragma unroll
        for (int s = 0; s < 4; ++s) zc[s] = zn[s];
    }
}

// ----------------------------------------------------------------- launch ---
extern "C" void kernel_launch(void* const* d_in, const int* in_sizes, int n_in,
                              void* d_out, int out_size, void* d_ws, size_t ws_size,
                              hipStream_t stream)
{
    const float* x   = (const float*)d_in[0];
    const float* We1 = (const float*)d_in[1];
    const float* be1 = (const float*)d_in[2];
    const float* We2 = (const float*)d_in[3];
    const float* be2 = (const float*)d_in[4];
    const float* We3 = (const float*)d_in[5];
    const float* be3 = (const float*)d_in[6];
    const float* We4 = (const float*)d_in[7];
    const float* be4 = (const float*)d_in[8];
    const float* Wd1 = (const float*)d_in[9];
    const float* bd1 = (const float*)d_in[10];
    const float* Wd2 = (const float*)d_in[11];
    const float* bd2 = (const float*)d_in[12];
    const float* Wd3 = (const float*)d_in[13];
    const float* bd3 = (const float*)d_in[14];
    const float* Wd4 = (const float*)d_in[15];
    const float* bd4 = (const float*)d_in[16];
    float* out = (float*)d_out;

    uint32_t* zpk = (uint32_t*)d_ws;   // 128 KB packed-fp16 z

    enc_kernel<<<NB / 8, 512, 0, stream>>>(x, We1, be1, We2, be2, We3, be3,
                                           We4, be4, zpk);
    dec_kernel<<<NU, 256, 0, stream>>>(zpk, Wd1, bd1, Wd2, bd2,
                                       Wd3, bd3, Wd4, bd4, out);
}